// Round 7
// baseline (424.219 us; speedup 1.0000x reference)
//
#include <hip/hip_runtime.h>

#define N_NODES 50000
#define N_EDGES 800000
#define D 128
#define C_OUT 10
#define BN_EPS 1e-5f
#define CAP 64            // padded adjacency row capacity; P(deg>=63)~1e-17 (Poisson 16)
#define MTILE 32          // R15: 32-row x 128-thr tiles (occ 23->40%)
#define GEMM_GRID 1563    // ceil(50000/32)
#define LINKB 782         // link blocks appended AFTER gemm tiles; 782*128*8 >= E
#define AGG_BLOCKS 2048   // 8 blocks/CU resident; whole grid co-resident
#define NCOPY 32          // BN-stats shadow copies (R13)
#define CSTR 136          // LDS C-dump row stride (ushorts): quad writes 2-way max

typedef unsigned int uint32;
typedef __attribute__((ext_vector_type(8))) short bf16x8;
typedef __attribute__((ext_vector_type(4))) float f32x4;

__device__ __forceinline__ float bf2f(unsigned int u16) {
    unsigned int x = u16 << 16;
    float f;
    __builtin_memcpy(&f, &x, 4);
    return f;
}
__device__ __forceinline__ unsigned int f2bf(float f) {
    unsigned int x;
    __builtin_memcpy(&x, &f, 4);
    unsigned int r = x + 0x7FFFu + ((x >> 16) & 1u);  // RNE
    return r >> 16;
}
__device__ __forceinline__ uint32 pack_bf2(float a, float b) {
    return f2bf(a) | (f2bf(b) << 16);
}

// ---------------- setup: W^T bf16, Wf^T bf16, cntp=0 (64B-padded), sums=0, done=0 ----

__global__ void k_setup(const float* __restrict__ W1, const float* __restrict__ W2,
                        const float* __restrict__ W3, const float* __restrict__ Wf,
                        unsigned short* __restrict__ WT, unsigned short* __restrict__ WfT,
                        int* __restrict__ cntp, float* __restrict__ sums,
                        int* __restrict__ done) {
    int b = blockIdx.x, tid = threadIdx.x;
    if (b < 192) {                       // WT: 3 x 128 x 128
        int idx = b * 256 + tid;
        int mat = idx >> 14, rem = idx & 16383;
        int n = rem >> 7, k = rem & 127;
        const float* W = (mat == 0) ? W1 : ((mat == 1) ? W2 : W3);
        WT[idx] = (unsigned short)f2bf(W[k * 128 + n]);
    } else if (b < 216) {                // WfT: 3 slices x 16(n,pad) x 128(k)
        int idx = (b - 192) * 256 + tid;
        if (idx < 6144) {
            int li = idx >> 11, rem = idx & 2047;
            int n = rem >> 7, k = rem & 127;
            WfT[idx] = (n < C_OUT) ? (unsigned short)f2bf(Wf[(li * 128 + k) * C_OUT + n]) : 0;
        }
    } else {                             // per-node atomic counter init + sums/done zero
        int i = (b - 216) * 256 + tid;
        if (i < N_NODES) cntp[i << 4] = 0;   // one counter per 64B line (atomic de-contention)
        if (i < 3 * NCOPY * 256) sums[i] = 0.0f;
        if (i < 3) done[i] = 0;
    }
}

// ---------------- compact deg: cnt (stored edges) + dinv = rsqrt(deg+1) ----------

__global__ void k_dinv(const int* __restrict__ cntp, int* __restrict__ cnt,
                       float* __restrict__ dinv) {
    int i = blockIdx.x * blockDim.x + threadIdx.x;
    if (i >= N_NODES) return;
    int c = cntp[i << 4];                        // in-edges (excl self)
    cnt[i] = (c < CAP) ? c : CAP;                // stored slots
    dinv[i] = rsqrtf((float)(c + 1));            // exact deg incl self (matches ref)
}

// ---------------- MFMA GEMM (+ optional fused direct adjacency build, BN prologue, readout)
// 32-row tiles, 128 threads (2 waves x 16 rows). hl[M,128](bf16) = bnrelu(A) @ W.
// R16: if dinvp != null, C-store pre-scales row gm by dinv[gm] (hl' = dinv*h) so the
// consumer agg skips its per-edge dinv load. Layer-1 gemm can't (dinv not built yet).
// A: Af32 (layer1) XOR Abf (bf16, BN'd via st). W read DIRECTLY from global WT (R14).
// C-tile: acc -> LDS (stride CSTR) -> coalesced uint4 store (R10).
// If linkEi: blocks [GEMM_GRID, GEMM_GRID+LINKB) do the direct slot build.
// mode: 0=none, 1=out = staged@WfT + bias, 2=out += staged@WfT.

__global__ __launch_bounds__(128) void k_gemm(const float* __restrict__ Af32,
                                              const unsigned short* __restrict__ Abf,
                                              const unsigned short* __restrict__ WT,
                                              unsigned short* __restrict__ hl,
                                              const float* __restrict__ st,
                                              const unsigned short* __restrict__ WfT,
                                              const float* __restrict__ bfv,
                                              float* __restrict__ outp, int mode,
                                              const float* __restrict__ dinvp,
                                              const int* __restrict__ linkEi,
                                              int* __restrict__ cntp,
                                              int* __restrict__ adj) {
    __shared__ unsigned short SM[MTILE * CSTR];   // 8.7 KB
    unsigned short* As = SM;
    int tid = threadIdx.x;
    int bid = blockIdx.x;

    if (linkEi && bid >= GEMM_GRID) {
        // direct adjacency build: 8 edges/thread, independent atomics (ILP)
        int lb = bid - GEMM_GRID;
        int d8[8], s8[8];
#pragma unroll
        for (int u = 0; u < 8; ++u) {
            int e = (lb * 8 + u) * 128 + tid;
            d8[u] = (e < N_EDGES) ? linkEi[N_EDGES + e] : -1;   // destination
            s8[u] = (e < N_EDGES) ? linkEi[e] : 0;              // source
        }
#pragma unroll
        for (int u = 0; u < 8; ++u) {
            if (d8[u] >= 0) {
                int slot = atomicAdd(&cntp[d8[u] << 4], 1);
                if (slot < CAP) adj[(d8[u] << 6) + slot] = s8[u];
            }
        }
        return;
    }
    int row0 = bid * MTILE;

    if (Abf) {
        // bf16 A path: thread stages 8 fixed columns cc..cc+7 (c8 = tid&15)
        int c8 = tid & 15, cc = c8 * 8;
        float s8[8], t8[8];
        {
            float4 a0 = *(const float4*)&st[cc];
            float4 a1 = *(const float4*)&st[cc + 4];
            float4 b0 = *(const float4*)&st[128 + cc];
            float4 b1 = *(const float4*)&st[128 + cc + 4];
            s8[0] = a0.x; s8[1] = a0.y; s8[2] = a0.z; s8[3] = a0.w;
            s8[4] = a1.x; s8[5] = a1.y; s8[6] = a1.z; s8[7] = a1.w;
            t8[0] = b0.x; t8[1] = b0.y; t8[2] = b0.z; t8[3] = b0.w;
            t8[4] = b1.x; t8[5] = b1.y; t8[6] = b1.z; t8[7] = b1.w;
        }
        const uint4* H4 = (const uint4*)Abf;
#pragma unroll
        for (int i = 0; i < 4; ++i) {
            int idx = i * 128 + tid;
            int r = idx >> 4;                   // 0..31
            int gr = row0 + r;
            uint4 v = make_uint4(0, 0, 0, 0);
            if (gr < N_NODES) v = H4[(size_t)gr * 16 + c8];
            uint32 w[4] = {v.x, v.y, v.z, v.w};
            uint32 o[4];
#pragma unroll
            for (int p = 0; p < 4; ++p) {
                float f0 = bf2f(w[p] & 0xFFFFu) * s8[2 * p] + t8[2 * p];
                float f1 = bf2f(w[p] >> 16) * s8[2 * p + 1] + t8[2 * p + 1];
                o[p] = pack_bf2(fmaxf(f0, 0.f), fmaxf(f1, 0.f));
            }
            int swz = c8 ^ (r & 15);
            *(uint4*)&As[r * 128 + swz * 8] = make_uint4(o[0], o[1], o[2], o[3]);
        }
    } else {
        // fp32 A path (layer 1: x, no BN)
        const float4* A4 = (const float4*)Af32;
        int c4 = tid & 31;
#pragma unroll
        for (int i = 0; i < 8; ++i) {
            int idx = i * 128 + tid;
            int r = idx >> 5;                   // 0..31
            int gr = row0 + r;
            float4 v = make_float4(0.f, 0.f, 0.f, 0.f);
            if (gr < N_NODES) v = A4[(size_t)gr * 32 + c4];
            ushort4 o;
            o.x = (unsigned short)f2bf(v.x);
            o.y = (unsigned short)f2bf(v.y);
            o.z = (unsigned short)f2bf(v.z);
            o.w = (unsigned short)f2bf(v.w);
            int swz = (c4 >> 1) ^ (r & 15);
            *(ushort4*)&As[r * 128 + swz * 8 + (c4 & 1) * 4] = o;
        }
    }
    __syncthreads();

    int wave = tid >> 6, lane = tid & 63;
    int quad = lane >> 4, l16 = lane & 15;
    int m0 = wave * 16;
    int m = m0 + l16;

    // a-frags: A[m][k = ks*32 + quad*8 + j]
    bf16x8 af[4];
#pragma unroll
    for (int ks = 0; ks < 4; ++ks) {
        int swz = (ks * 4 + quad) ^ (m & 15);
        af[ks] = *(bf16x8*)&As[m * 128 + swz * 8];
    }

    f32x4 acc[8];
#pragma unroll
    for (int nt = 0; nt < 8; ++nt) acc[nt] = (f32x4){0.f, 0.f, 0.f, 0.f};

#pragma unroll
    for (int nt = 0; nt < 8; ++nt) {
        int n = nt * 16 + l16;
        bf16x8 bfr[4];
#pragma unroll
        for (int ks = 0; ks < 4; ++ks)
            bfr[ks] = *(const bf16x8*)&WT[n * 128 + (ks * 4 + quad) * 8];  // global, L2-hot
#pragma unroll
        for (int ks = 0; ks < 4; ++ks)
            acc[nt] = __builtin_amdgcn_mfma_f32_16x16x32_bf16(af[ks], bfr[ks], acc[nt], 0, 0, 0);
    }

    // fused readout partial: out (=|+=) staged @ WfT (+bias). 4 extra MFMAs.
    if (mode != 0) {
        f32x4 accO = (f32x4){0.f, 0.f, 0.f, 0.f};
#pragma unroll
        for (int ks = 0; ks < 4; ++ks) {
            bf16x8 bw = *(const bf16x8*)&WfT[l16 * 128 + (ks * 4 + quad) * 8];  // tiny, L2-hot
            accO = __builtin_amdgcn_mfma_f32_16x16x32_bf16(af[ks], bw, accO, 0, 0, 0);
        }
        if (l16 < C_OUT) {
#pragma unroll
            for (int reg = 0; reg < 4; ++reg) {
                int gm = row0 + m0 + quad * 4 + reg;
                if (gm < N_NODES) {
                    size_t o = (size_t)gm * C_OUT + l16;
                    float v = accO[reg];
                    if (mode == 1) outp[o] = v + bfv[l16];
                    else outp[o] += v;
                }
            }
        }
    }

    // optional dinv pre-scale factors for this thread's 4 output rows (R16)
    float dv[4] = {1.f, 1.f, 1.f, 1.f};
    if (dinvp) {
#pragma unroll
        for (int reg = 0; reg < 4; ++reg) {
            int gm = row0 + m0 + quad * 4 + reg;
            dv[reg] = (gm < N_NODES) ? dinvp[gm] : 0.f;
        }
    }

    // C-tile: acc -> LDS (bf16, stride CSTR) -> coalesced uint4 stores (full lines)
    __syncthreads();   // all waves done reading As
#pragma unroll
    for (int reg = 0; reg < 4; ++reg) {
        int lm = m0 + quad * 4 + reg;    // local row 0..31
#pragma unroll
        for (int nt = 0; nt < 8; ++nt)
            SM[lm * CSTR + nt * 16 + l16] = (unsigned short)f2bf(acc[nt][reg] * dv[reg]);
    }
    __syncthreads();
    uint4* H4o = (uint4*)hl;
#pragma unroll
    for (int i = 0; i < 4; ++i) {
        int idx = i * 128 + tid;
        int r = idx >> 4, c8 = idx & 15;
        int gr = row0 + r;
        if (gr < N_NODES)
            H4o[(size_t)gr * 16 + c8] = *(uint4*)&SM[r * CSTR + c8 * 8];
    }
}

// ---------------- Aggregation: wave/node grid-stride, unroll-8, bf16 out,
// FUSED BN stats (LDS reduce -> NCOPY shadow atomicAdd) and FUSED bnfin via
// last-block ticket (R16): last block fences (acquire, own-XCD L2 inv) and
// reduces the shadow copies -> st scale/shift. Producers' atomics are
// device-scope; __syncthreads drains each thread's atomic before the ticket.
// scaled=1: hl rows are pre-scaled by dinv (layers 2/3) -> no per-edge dinv load.

__global__ __launch_bounds__(256) void k_agg(const unsigned short* __restrict__ hl,
                                             const int* __restrict__ adj,
                                             const int* __restrict__ cnt,
                                             const float* __restrict__ dinv,
                                             unsigned short* __restrict__ agg,
                                             float* __restrict__ sums,
                                             const float* __restrict__ g,
                                             const float* __restrict__ be,
                                             float* __restrict__ st,
                                             int* __restrict__ done,
                                             int scaled) {
    __shared__ float red[4][256];
    __shared__ int lastFlag;
    int tid = threadIdx.x;
    int lane = tid & 63;
    int gw = (blockIdx.x << 2) | (tid >> 6);      // global wave id
    float sx = 0.f, qx = 0.f, sy = 0.f, qy = 0.f;

    for (int node = gw; node < N_NODES; node += AGG_BLOCKS * 4) {
        const int* row = adj + ((size_t)node << 6);   // wave-uniform scalar reads
        int n = cnt[node];
        float di = dinv[node];
        uint32 ps = *(const uint32*)&hl[(size_t)node * 128 + lane * 2];
        float ax, ay;
        if (scaled) {                                 // hl already dinv-scaled
            ax = bf2f(ps & 0xFFFFu);
            ay = bf2f(ps >> 16);
        } else {
            ax = bf2f(ps & 0xFFFFu) * di;
            ay = bf2f(ps >> 16) * di;
        }
        int e = 0;
        for (; e + 7 < n; e += 8) {
            int j[8];
#pragma unroll
            for (int u = 0; u < 8; ++u) j[u] = row[e + u];
            uint32 p[8];
#pragma unroll
            for (int u = 0; u < 8; ++u)
                p[u] = *(const uint32*)&hl[(size_t)j[u] * 128 + lane * 2];
            if (scaled) {
#pragma unroll
                for (int u = 0; u < 8; ++u) {
                    ax += bf2f(p[u] & 0xFFFFu);
                    ay += bf2f(p[u] >> 16);
                }
            } else {
                float w[8];
#pragma unroll
                for (int u = 0; u < 8; ++u) w[u] = dinv[j[u]];
#pragma unroll
                for (int u = 0; u < 8; ++u) {
                    ax += bf2f(p[u] & 0xFFFFu) * w[u];
                    ay += bf2f(p[u] >> 16) * w[u];
                }
            }
        }
        for (; e < n; ++e) {
            int j = row[e];
            uint32 p = *(const uint32*)&hl[(size_t)j * 128 + lane * 2];
            if (scaled) {
                ax += bf2f(p & 0xFFFFu);
                ay += bf2f(p >> 16);
            } else {
                float w = dinv[j];
                ax += bf2f(p & 0xFFFFu) * w;
                ay += bf2f(p >> 16) * w;
            }
        }
        float ox = ax * di, oy = ay * di;
        *(uint32*)&agg[(size_t)node * 128 + lane * 2] = pack_bf2(ox, oy);
        sx += ox; qx += ox * ox; sy += oy; qy += oy * oy;
    }

    red[0][tid] = sx; red[1][tid] = qx; red[2][tid] = sy; red[3][tid] = qy;
    __syncthreads();
    int s = tid >> 6, l = tid & 63;
    float v = red[s][l] + red[s][64 + l] + red[s][128 + l] + red[s][192 + l];
    atomicAdd(&sums[((blockIdx.x & (NCOPY - 1)) << 8) + (s & 1) * 128 + 2 * l + (s >> 1)], v);

    // ---- fused BN finalize: last block reduces NCOPY copies -> st ----
    __syncthreads();   // drains every thread's vmcnt (incl. the stats atomic)
    if (tid == 0) lastFlag = (atomicAdd(done, 1) == AGG_BLOCKS - 1) ? 1 : 0;
    __syncthreads();
    if (lastFlag) {
        __threadfence();           // acquire: invalidate this XCD's caches
        if (tid < 128) {
            float sm = 0.f, sq = 0.f;
            for (int c = 0; c < NCOPY; ++c) {
                sm += sums[c * 256 + tid];
                sq += sums[c * 256 + 128 + tid];
            }
            float mean = sm * (1.0f / N_NODES);
            float var = fmaxf(sq * (1.0f / N_NODES) - mean * mean, 0.f);
            float sc = g[tid] * rsqrtf(var + BN_EPS);
            st[tid] = sc;
            st[128 + tid] = be[tid] - mean * sc;
        }
    }
}

// ---------------- Layer-3 readout: MFMA, out += bnrelu(h3) @ WfT-slice2 (32-row tiles) ----

__global__ __launch_bounds__(128) void k_out_mfma(const unsigned short* __restrict__ h,
                                                  const unsigned short* __restrict__ WfT,
                                                  float* __restrict__ outp,
                                                  const float* __restrict__ st) {
    __shared__ unsigned short As[MTILE * 128];  // 8 KB
    int tid = threadIdx.x;
    int row0 = blockIdx.x * MTILE;

    int c8 = tid & 15, cc = c8 * 8;
    float s8[8], t8[8];
    {
        float4 a0 = *(const float4*)&st[cc];
        float4 a1 = *(const float4*)&st[cc + 4];
        float4 b0 = *(const float4*)&st[128 + cc];
        float4 b1 = *(const float4*)&st[128 + cc + 4];
        s8[0] = a0.x; s8[1] = a0.y; s8[2] = a0.z; s8[3] = a0.w;
        s8[4] = a1.x; s8[5] = a1.y; s8[6] = a1.z; s8[7] = a1.w;
        t8[0] = b0.x; t8[1] = b0.y; t8[2] = b0.z; t8[3] = b0.w;
        t8[4] = b1.x; t8[5] = b1.y; t8[6] = b1.z; t8[7] = b1.w;
    }
    const uint4* H4 = (const uint4*)h;
#pragma unroll
    for (int i = 0; i < 4; ++i) {
        int idx = i * 128 + tid;
        int r = idx >> 4;
        int gr = row0 + r;
        uint4 v = make_uint4(0, 0, 0, 0);
        if (gr < N_NODES) v = H4[(size_t)gr * 16 + c8];
        uint32 w[4] = {v.x, v.y, v.z, v.w};
        uint32 o[4];
#pragma unroll
        for (int p = 0; p < 4; ++p) {
            float f0 = bf2f(w[p] & 0xFFFFu) * s8[2 * p] + t8[2 * p];
            float f1 = bf2f(w[p] >> 16) * s8[2 * p + 1] + t8[2 * p + 1];
            o[p] = pack_bf2(fmaxf(f0, 0.f), fmaxf(f1, 0.f));
        }
        int swz = c8 ^ (r & 15);
        *(uint4*)&As[r * 128 + swz * 8] = make_uint4(o[0], o[1], o[2], o[3]);
    }
    __syncthreads();

    int wave = tid >> 6, lane = tid & 63;
    int quad = lane >> 4, l16 = lane & 15;
    int m0 = wave * 16;
    int m = m0 + l16;

    f32x4 accO = (f32x4){0.f, 0.f, 0.f, 0.f};
#pragma unroll
    for (int ks = 0; ks < 4; ++ks) {
        bf16x8 bw = *(const bf16x8*)&WfT[l16 * 128 + (ks * 4 + quad) * 8];
        int swz = (ks * 4 + quad) ^ (m & 15);
        bf16x8 av = *(bf16x8*)&As[m * 128 + swz * 8];
        accO = __builtin_amdgcn_mfma_f32_16x16x32_bf16(av, bw, accO, 0, 0, 0);
    }
    if (l16 < C_OUT) {
#pragma unroll
        for (int reg = 0; reg < 4; ++reg) {
            int gm = row0 + m0 + quad * 4 + reg;
            if (gm < N_NODES)
                outp[(size_t)gm * C_OUT + l16] += accO[reg];
        }
    }
}

// ---------------- launch ----------------

extern "C" void kernel_launch(void* const* d_in, const int* in_sizes, int n_in,
                              void* d_out, int out_size, void* d_ws, size_t ws_size,
                              hipStream_t stream) {
    const float* x  = (const float*)d_in[0];
    const int*   ei = (const int*)d_in[1];
    const float* W1 = (const float*)d_in[2];
    const float* W2 = (const float*)d_in[4];
    const float* W3 = (const float*)d_in[6];
    // b1/b2/b3 absorbed exactly by BN mean-subtraction
    const float* g1  = (const float*)d_in[8];
    const float* be1 = (const float*)d_in[9];
    const float* g2  = (const float*)d_in[10];
    const float* be2 = (const float*)d_in[11];
    const float* g3  = (const float*)d_in[12];
    const float* be3 = (const float*)d_in[13];
    const float* Wf  = (const float*)d_in[14];
    const float* bf  = (const float*)d_in[15];
    float* out = (float*)d_out;

    char* ws = (char*)d_ws;
    size_t off = 0;
    auto alloc = [&](size_t bytes) -> void* {
        void* p = ws + off;
        off = (off + bytes + 255) & ~(size_t)255;
        return p;
    };
    int*   cntp  = (int*)alloc((size_t)N_NODES * 16 * 4);    // 64B-padded counters, 3.2MB
    int*   adj   = (int*)alloc((size_t)N_NODES * CAP * 4);   // 12.8 MB padded rows
    int*   cnt   = (int*)alloc((size_t)N_NODES * 4);
    float* dinv  = (float*)alloc((size_t)N_NODES * 4);
    float* sums  = (float*)alloc((size_t)3 * NCOPY * 256 * 4);  // shadow-copied stats
    float* st    = (float*)alloc((size_t)3 * 256 * 4);          // precomputed BN scale/shift
    int*   done  = (int*)alloc(3 * 4);                          // agg last-block tickets
    unsigned short* WT   = (unsigned short*)alloc((size_t)3 * 128 * 128 * 2);
    unsigned short* WfT  = (unsigned short*)alloc((size_t)3 * 16 * 128 * 2);
    unsigned short* hl   = (unsigned short*)alloc((size_t)N_NODES * 128 * 2);  // bf16
    unsigned short* bufA = (unsigned short*)alloc((size_t)N_NODES * 128 * 2);  // bf16 agg
    unsigned short* bufB = (unsigned short*)alloc((size_t)N_NODES * 128 * 2);  // bf16 agg

    const int TPB = 256;
    const int SL = NCOPY * 256;   // per-layer sums stride
    k_setup<<<412, 256, 0, stream>>>(W1, W2, W3, Wf, WT, WfT, cntp, sums, done);

    // ---- layer 1 GEMM fused with direct adjacency build (gemm tiles FIRST) ----
    k_gemm<<<GEMM_GRID + LINKB, 128, 0, stream>>>(
        x, nullptr, WT, hl, nullptr, nullptr,
        nullptr, nullptr, 0, nullptr, ei, cntp, adj);
    k_dinv<<<(N_NODES + TPB - 1) / TPB, TPB, 0, stream>>>(cntp, cnt, dinv);
    k_agg<<<AGG_BLOCKS, 256, 0, stream>>>(hl, adj, cnt, dinv, bufA, sums + 0,
                                          g1, be1, st + 0, done + 0, 0);

    // ---- layer 2 (gemm also emits out = h1 @ Wf0 + bf; hl pre-scaled by dinv) ----
    k_gemm<<<GEMM_GRID, 128, 0, stream>>>(nullptr, bufA, WT + 16384, hl, st + 0,
                                          WfT, bf, out, 1, dinv, nullptr, nullptr, nullptr);
    k_agg<<<AGG_BLOCKS, 256, 0, stream>>>(hl, adj, cnt, dinv, bufB, sums + SL,
                                          g2, be2, st + 256, done + 1, 1);

    // ---- layer 3 (gemm also emits out += h2 @ Wf1; hl pre-scaled by dinv) ----
    k_gemm<<<GEMM_GRID, 128, 0, stream>>>(nullptr, bufB, WT + 32768, hl, st + 256,
                                          WfT + 2048, nullptr, out, 2, dinv,
                                          nullptr, nullptr, nullptr);
    k_agg<<<AGG_BLOCKS, 256, 0, stream>>>(hl, adj, cnt, dinv, bufA, sums + 2 * SL,
                                          g3, be3, st + 512, done + 2, 1);

    // ---- layer 3 readout (MFMA) ----
    k_out_mfma<<<GEMM_GRID, 128, 0, stream>>>(bufA, WfT + 4096, out, st + 512);
}

// Round 8
// 397.577 us; speedup vs baseline: 1.0670x; 1.0670x over previous
//
#include <hip/hip_runtime.h>

#define N_NODES 50000
#define N_EDGES 800000
#define D 128
#define C_OUT 10
#define BN_EPS 1e-5f
#define CAP 64            // padded adjacency row capacity; P(deg>=63)~1e-17 (Poisson 16)
#define MTILE 32          // R15: 32-row x 128-thr tiles (occ 23->40%)
#define GEMM_GRID 1563    // ceil(50000/32)
#define LINKB 782         // link blocks appended AFTER gemm tiles; 782*128*8 >= E
#define AGG_BLOCKS 2048   // 8 blocks/CU resident; whole grid co-resident
#define NCOPY 32          // BN-stats shadow copies (R13)
#define CSTR 136          // LDS C-dump row stride (ushorts): quad writes 2-way max

// R17: last-block-ticket bnfin fusion REVERTED — 2048 value-returning atomics to one
// address serialized ~25-30us onto every agg block's tail (R13 lesson, signal address
// edition). Standalone k_bnfin (~4us incl gap) is strictly cheaper.

typedef unsigned int uint32;
typedef __attribute__((ext_vector_type(8))) short bf16x8;
typedef __attribute__((ext_vector_type(4))) float f32x4;

__device__ __forceinline__ float bf2f(unsigned int u16) {
    unsigned int x = u16 << 16;
    float f;
    __builtin_memcpy(&f, &x, 4);
    return f;
}
__device__ __forceinline__ unsigned int f2bf(float f) {
    unsigned int x;
    __builtin_memcpy(&x, &f, 4);
    unsigned int r = x + 0x7FFFu + ((x >> 16) & 1u);  // RNE
    return r >> 16;
}
__device__ __forceinline__ uint32 pack_bf2(float a, float b) {
    return f2bf(a) | (f2bf(b) << 16);
}

// ---------------- setup: W^T bf16, Wf^T bf16, cntp=0 (64B-padded), sums=0 ----------

__global__ void k_setup(const float* __restrict__ W1, const float* __restrict__ W2,
                        const float* __restrict__ W3, const float* __restrict__ Wf,
                        unsigned short* __restrict__ WT, unsigned short* __restrict__ WfT,
                        int* __restrict__ cntp, float* __restrict__ sums) {
    int b = blockIdx.x, tid = threadIdx.x;
    if (b < 192) {                       // WT: 3 x 128 x 128
        int idx = b * 256 + tid;
        int mat = idx >> 14, rem = idx & 16383;
        int n = rem >> 7, k = rem & 127;
        const float* W = (mat == 0) ? W1 : ((mat == 1) ? W2 : W3);
        WT[idx] = (unsigned short)f2bf(W[k * 128 + n]);
    } else if (b < 216) {                // WfT: 3 slices x 16(n,pad) x 128(k)
        int idx = (b - 192) * 256 + tid;
        if (idx < 6144) {
            int li = idx >> 11, rem = idx & 2047;
            int n = rem >> 7, k = rem & 127;
            WfT[idx] = (n < C_OUT) ? (unsigned short)f2bf(Wf[(li * 128 + k) * C_OUT + n]) : 0;
        }
    } else {                             // per-node atomic counter init + sums zero
        int i = (b - 216) * 256 + tid;
        if (i < N_NODES) cntp[i << 4] = 0;   // one counter per 64B line (atomic de-contention)
        if (i < 3 * NCOPY * 256) sums[i] = 0.0f;
    }
}

// ---------------- compact deg: cnt (stored edges) + dinv = rsqrt(deg+1) ----------

__global__ void k_dinv(const int* __restrict__ cntp, int* __restrict__ cnt,
                       float* __restrict__ dinv) {
    int i = blockIdx.x * blockDim.x + threadIdx.x;
    if (i >= N_NODES) return;
    int c = cntp[i << 4];                        // in-edges (excl self)
    cnt[i] = (c < CAP) ? c : CAP;                // stored slots
    dinv[i] = rsqrtf((float)(c + 1));            // exact deg incl self (matches ref)
}

// ---------------- BN finalize: reduce NCOPY shadow copies -> scale/shift st[2][128] ----

__global__ void k_bnfin(const float* __restrict__ sums, const float* __restrict__ g,
                        const float* __restrict__ be, float* __restrict__ st) {
    int t = threadIdx.x;      // 128 threads
    float sm = 0.f, sq = 0.f;
    for (int c = 0; c < NCOPY; ++c) {
        sm += sums[c * 256 + t];
        sq += sums[c * 256 + 128 + t];
    }
    float mean = sm * (1.0f / N_NODES);
    float var = fmaxf(sq * (1.0f / N_NODES) - mean * mean, 0.f);
    float s = g[t] * rsqrtf(var + BN_EPS);
    st[t] = s;
    st[128 + t] = be[t] - mean * s;
}

// ---------------- MFMA GEMM (+ optional fused direct adjacency build, BN prologue, readout)
// 32-row tiles, 128 threads (2 waves x 16 rows). hl[M,128](bf16) = bnrelu(A) @ W.
// R16: if dinvp != null, C-store pre-scales row gm by dinv[gm] (hl' = dinv*h) so the
// consumer agg skips its per-edge dinv load. Layer-1 gemm can't (dinv not built yet).
// A: Af32 (layer1) XOR Abf (bf16, BN'd via st). W read DIRECTLY from global WT (R14).
// C-tile: acc -> LDS (stride CSTR) -> coalesced uint4 store (R10).
// If linkEi: blocks [GEMM_GRID, GEMM_GRID+LINKB) do the direct slot build.
// mode: 0=none, 1=out = staged@WfT + bias, 2=out += staged@WfT.

__global__ __launch_bounds__(128) void k_gemm(const float* __restrict__ Af32,
                                              const unsigned short* __restrict__ Abf,
                                              const unsigned short* __restrict__ WT,
                                              unsigned short* __restrict__ hl,
                                              const float* __restrict__ st,
                                              const unsigned short* __restrict__ WfT,
                                              const float* __restrict__ bfv,
                                              float* __restrict__ outp, int mode,
                                              const float* __restrict__ dinvp,
                                              const int* __restrict__ linkEi,
                                              int* __restrict__ cntp,
                                              int* __restrict__ adj) {
    __shared__ unsigned short SM[MTILE * CSTR];   // 8.7 KB
    unsigned short* As = SM;
    int tid = threadIdx.x;
    int bid = blockIdx.x;

    if (linkEi && bid >= GEMM_GRID) {
        // direct adjacency build: 8 edges/thread, independent atomics (ILP)
        int lb = bid - GEMM_GRID;
        int d8[8], s8[8];
#pragma unroll
        for (int u = 0; u < 8; ++u) {
            int e = (lb * 8 + u) * 128 + tid;
            d8[u] = (e < N_EDGES) ? linkEi[N_EDGES + e] : -1;   // destination
            s8[u] = (e < N_EDGES) ? linkEi[e] : 0;              // source
        }
#pragma unroll
        for (int u = 0; u < 8; ++u) {
            if (d8[u] >= 0) {
                int slot = atomicAdd(&cntp[d8[u] << 4], 1);
                if (slot < CAP) adj[(d8[u] << 6) + slot] = s8[u];
            }
        }
        return;
    }
    int row0 = bid * MTILE;

    if (Abf) {
        // bf16 A path: thread stages 8 fixed columns cc..cc+7 (c8 = tid&15)
        int c8 = tid & 15, cc = c8 * 8;
        float s8[8], t8[8];
        {
            float4 a0 = *(const float4*)&st[cc];
            float4 a1 = *(const float4*)&st[cc + 4];
            float4 b0 = *(const float4*)&st[128 + cc];
            float4 b1 = *(const float4*)&st[128 + cc + 4];
            s8[0] = a0.x; s8[1] = a0.y; s8[2] = a0.z; s8[3] = a0.w;
            s8[4] = a1.x; s8[5] = a1.y; s8[6] = a1.z; s8[7] = a1.w;
            t8[0] = b0.x; t8[1] = b0.y; t8[2] = b0.z; t8[3] = b0.w;
            t8[4] = b1.x; t8[5] = b1.y; t8[6] = b1.z; t8[7] = b1.w;
        }
        const uint4* H4 = (const uint4*)Abf;
#pragma unroll
        for (int i = 0; i < 4; ++i) {
            int idx = i * 128 + tid;
            int r = idx >> 4;                   // 0..31
            int gr = row0 + r;
            uint4 v = make_uint4(0, 0, 0, 0);
            if (gr < N_NODES) v = H4[(size_t)gr * 16 + c8];
            uint32 w[4] = {v.x, v.y, v.z, v.w};
            uint32 o[4];
#pragma unroll
            for (int p = 0; p < 4; ++p) {
                float f0 = bf2f(w[p] & 0xFFFFu) * s8[2 * p] + t8[2 * p];
                float f1 = bf2f(w[p] >> 16) * s8[2 * p + 1] + t8[2 * p + 1];
                o[p] = pack_bf2(fmaxf(f0, 0.f), fmaxf(f1, 0.f));
            }
            int swz = c8 ^ (r & 15);
            *(uint4*)&As[r * 128 + swz * 8] = make_uint4(o[0], o[1], o[2], o[3]);
        }
    } else {
        // fp32 A path (layer 1: x, no BN)
        const float4* A4 = (const float4*)Af32;
        int c4 = tid & 31;
#pragma unroll
        for (int i = 0; i < 8; ++i) {
            int idx = i * 128 + tid;
            int r = idx >> 5;                   // 0..31
            int gr = row0 + r;
            float4 v = make_float4(0.f, 0.f, 0.f, 0.f);
            if (gr < N_NODES) v = A4[(size_t)gr * 32 + c4];
            ushort4 o;
            o.x = (unsigned short)f2bf(v.x);
            o.y = (unsigned short)f2bf(v.y);
            o.z = (unsigned short)f2bf(v.z);
            o.w = (unsigned short)f2bf(v.w);
            int swz = (c4 >> 1) ^ (r & 15);
            *(ushort4*)&As[r * 128 + swz * 8 + (c4 & 1) * 4] = o;
        }
    }
    __syncthreads();

    int wave = tid >> 6, lane = tid & 63;
    int quad = lane >> 4, l16 = lane & 15;
    int m0 = wave * 16;
    int m = m0 + l16;

    // a-frags: A[m][k = ks*32 + quad*8 + j]
    bf16x8 af[4];
#pragma unroll
    for (int ks = 0; ks < 4; ++ks) {
        int swz = (ks * 4 + quad) ^ (m & 15);
        af[ks] = *(bf16x8*)&As[m * 128 + swz * 8];
    }

    f32x4 acc[8];
#pragma unroll
    for (int nt = 0; nt < 8; ++nt) acc[nt] = (f32x4){0.f, 0.f, 0.f, 0.f};

#pragma unroll
    for (int nt = 0; nt < 8; ++nt) {
        int n = nt * 16 + l16;
        bf16x8 bfr[4];
#pragma unroll
        for (int ks = 0; ks < 4; ++ks)
            bfr[ks] = *(const bf16x8*)&WT[n * 128 + (ks * 4 + quad) * 8];  // global, L2-hot
#pragma unroll
        for (int ks = 0; ks < 4; ++ks)
            acc[nt] = __builtin_amdgcn_mfma_f32_16x16x32_bf16(af[ks], bfr[ks], acc[nt], 0, 0, 0);
    }

    // fused readout partial: out (=|+=) staged @ WfT (+bias). 4 extra MFMAs.
    if (mode != 0) {
        f32x4 accO = (f32x4){0.f, 0.f, 0.f, 0.f};
#pragma unroll
        for (int ks = 0; ks < 4; ++ks) {
            bf16x8 bw = *(const bf16x8*)&WfT[l16 * 128 + (ks * 4 + quad) * 8];  // tiny, L2-hot
            accO = __builtin_amdgcn_mfma_f32_16x16x32_bf16(af[ks], bw, accO, 0, 0, 0);
        }
        if (l16 < C_OUT) {
#pragma unroll
            for (int reg = 0; reg < 4; ++reg) {
                int gm = row0 + m0 + quad * 4 + reg;
                if (gm < N_NODES) {
                    size_t o = (size_t)gm * C_OUT + l16;
                    float v = accO[reg];
                    if (mode == 1) outp[o] = v + bfv[l16];
                    else outp[o] += v;
                }
            }
        }
    }

    // optional dinv pre-scale factors for this thread's 4 output rows (R16)
    float dv[4] = {1.f, 1.f, 1.f, 1.f};
    if (dinvp) {
#pragma unroll
        for (int reg = 0; reg < 4; ++reg) {
            int gm = row0 + m0 + quad * 4 + reg;
            dv[reg] = (gm < N_NODES) ? dinvp[gm] : 0.f;
        }
    }

    // C-tile: acc -> LDS (bf16, stride CSTR) -> coalesced uint4 stores (full lines)
    __syncthreads();   // all waves done reading As
#pragma unroll
    for (int reg = 0; reg < 4; ++reg) {
        int lm = m0 + quad * 4 + reg;    // local row 0..31
#pragma unroll
        for (int nt = 0; nt < 8; ++nt)
            SM[lm * CSTR + nt * 16 + l16] = (unsigned short)f2bf(acc[nt][reg] * dv[reg]);
    }
    __syncthreads();
    uint4* H4o = (uint4*)hl;
#pragma unroll
    for (int i = 0; i < 4; ++i) {
        int idx = i * 128 + tid;
        int r = idx >> 4, c8 = idx & 15;
        int gr = row0 + r;
        if (gr < N_NODES)
            H4o[(size_t)gr * 16 + c8] = *(uint4*)&SM[r * CSTR + c8 * 8];
    }
}

// ---------------- Aggregation: wave/node grid-stride, unroll-8, bf16 out,
// FUSED BN stats (LDS reduce -> NCOPY shadow atomicAdd; depth-64 chains ~3us).
// scaled=1: hl rows pre-scaled by dinv (layers 2/3) -> no per-edge dinv load.

__global__ __launch_bounds__(256) void k_agg(const unsigned short* __restrict__ hl,
                                             const int* __restrict__ adj,
                                             const int* __restrict__ cnt,
                                             const float* __restrict__ dinv,
                                             unsigned short* __restrict__ agg,
                                             float* __restrict__ sums,
                                             int scaled) {
    __shared__ float red[4][256];
    int tid = threadIdx.x;
    int lane = tid & 63;
    int gw = (blockIdx.x << 2) | (tid >> 6);      // global wave id
    float sx = 0.f, qx = 0.f, sy = 0.f, qy = 0.f;

    for (int node = gw; node < N_NODES; node += AGG_BLOCKS * 4) {
        const int* row = adj + ((size_t)node << 6);   // wave-uniform scalar reads
        int n = cnt[node];
        float di = dinv[node];
        uint32 ps = *(const uint32*)&hl[(size_t)node * 128 + lane * 2];
        float ax, ay;
        if (scaled) {                                 // hl already dinv-scaled
            ax = bf2f(ps & 0xFFFFu);
            ay = bf2f(ps >> 16);
        } else {
            ax = bf2f(ps & 0xFFFFu) * di;
            ay = bf2f(ps >> 16) * di;
        }
        int e = 0;
        for (; e + 7 < n; e += 8) {
            int j[8];
#pragma unroll
            for (int u = 0; u < 8; ++u) j[u] = row[e + u];
            uint32 p[8];
#pragma unroll
            for (int u = 0; u < 8; ++u)
                p[u] = *(const uint32*)&hl[(size_t)j[u] * 128 + lane * 2];
            if (scaled) {
#pragma unroll
                for (int u = 0; u < 8; ++u) {
                    ax += bf2f(p[u] & 0xFFFFu);
                    ay += bf2f(p[u] >> 16);
                }
            } else {
                float w[8];
#pragma unroll
                for (int u = 0; u < 8; ++u) w[u] = dinv[j[u]];
#pragma unroll
                for (int u = 0; u < 8; ++u) {
                    ax += bf2f(p[u] & 0xFFFFu) * w[u];
                    ay += bf2f(p[u] >> 16) * w[u];
                }
            }
        }
        for (; e < n; ++e) {
            int j = row[e];
            uint32 p = *(const uint32*)&hl[(size_t)j * 128 + lane * 2];
            if (scaled) {
                ax += bf2f(p & 0xFFFFu);
                ay += bf2f(p >> 16);
            } else {
                float w = dinv[j];
                ax += bf2f(p & 0xFFFFu) * w;
                ay += bf2f(p >> 16) * w;
            }
        }
        float ox = ax * di, oy = ay * di;
        *(uint32*)&agg[(size_t)node * 128 + lane * 2] = pack_bf2(ox, oy);
        sx += ox; qx += ox * ox; sy += oy; qy += oy * oy;
    }

    red[0][tid] = sx; red[1][tid] = qx; red[2][tid] = sy; red[3][tid] = qy;
    __syncthreads();
    int s = tid >> 6, l = tid & 63;
    float v = red[s][l] + red[s][64 + l] + red[s][128 + l] + red[s][192 + l];
    atomicAdd(&sums[((blockIdx.x & (NCOPY - 1)) << 8) + (s & 1) * 128 + 2 * l + (s >> 1)], v);
}

// ---------------- Layer-3 readout: MFMA, out += bnrelu(h3) @ WfT-slice2 (32-row tiles) ----

__global__ __launch_bounds__(128) void k_out_mfma(const unsigned short* __restrict__ h,
                                                  const unsigned short* __restrict__ WfT,
                                                  float* __restrict__ outp,
                                                  const float* __restrict__ st) {
    __shared__ unsigned short As[MTILE * 128];  // 8 KB
    int tid = threadIdx.x;
    int row0 = blockIdx.x * MTILE;

    int c8 = tid & 15, cc = c8 * 8;
    float s8[8], t8[8];
    {
        float4 a0 = *(const float4*)&st[cc];
        float4 a1 = *(const float4*)&st[cc + 4];
        float4 b0 = *(const float4*)&st[128 + cc];
        float4 b1 = *(const float4*)&st[128 + cc + 4];
        s8[0] = a0.x; s8[1] = a0.y; s8[2] = a0.z; s8[3] = a0.w;
        s8[4] = a1.x; s8[5] = a1.y; s8[6] = a1.z; s8[7] = a1.w;
        t8[0] = b0.x; t8[1] = b0.y; t8[2] = b0.z; t8[3] = b0.w;
        t8[4] = b1.x; t8[5] = b1.y; t8[6] = b1.z; t8[7] = b1.w;
    }
    const uint4* H4 = (const uint4*)h;
#pragma unroll
    for (int i = 0; i < 4; ++i) {
        int idx = i * 128 + tid;
        int r = idx >> 4;
        int gr = row0 + r;
        uint4 v = make_uint4(0, 0, 0, 0);
        if (gr < N_NODES) v = H4[(size_t)gr * 16 + c8];
        uint32 w[4] = {v.x, v.y, v.z, v.w};
        uint32 o[4];
#pragma unroll
        for (int p = 0; p < 4; ++p) {
            float f0 = bf2f(w[p] & 0xFFFFu) * s8[2 * p] + t8[2 * p];
            float f1 = bf2f(w[p] >> 16) * s8[2 * p + 1] + t8[2 * p + 1];
            o[p] = pack_bf2(fmaxf(f0, 0.f), fmaxf(f1, 0.f));
        }
        int swz = c8 ^ (r & 15);
        *(uint4*)&As[r * 128 + swz * 8] = make_uint4(o[0], o[1], o[2], o[3]);
    }
    __syncthreads();

    int wave = tid >> 6, lane = tid & 63;
    int quad = lane >> 4, l16 = lane & 15;
    int m0 = wave * 16;
    int m = m0 + l16;

    f32x4 accO = (f32x4){0.f, 0.f, 0.f, 0.f};
#pragma unroll
    for (int ks = 0; ks < 4; ++ks) {
        bf16x8 bw = *(const bf16x8*)&WfT[l16 * 128 + (ks * 4 + quad) * 8];
        int swz = (ks * 4 + quad) ^ (m & 15);
        bf16x8 av = *(bf16x8*)&As[m * 128 + swz * 8];
        accO = __builtin_amdgcn_mfma_f32_16x16x32_bf16(av, bw, accO, 0, 0, 0);
    }
    if (l16 < C_OUT) {
#pragma unroll
        for (int reg = 0; reg < 4; ++reg) {
            int gm = row0 + m0 + quad * 4 + reg;
            if (gm < N_NODES)
                outp[(size_t)gm * C_OUT + l16] += accO[reg];
        }
    }
}

// ---------------- launch ----------------

extern "C" void kernel_launch(void* const* d_in, const int* in_sizes, int n_in,
                              void* d_out, int out_size, void* d_ws, size_t ws_size,
                              hipStream_t stream) {
    const float* x  = (const float*)d_in[0];
    const int*   ei = (const int*)d_in[1];
    const float* W1 = (const float*)d_in[2];
    const float* W2 = (const float*)d_in[4];
    const float* W3 = (const float*)d_in[6];
    // b1/b2/b3 absorbed exactly by BN mean-subtraction
    const float* g1  = (const float*)d_in[8];
    const float* be1 = (const float*)d_in[9];
    const float* g2  = (const float*)d_in[10];
    const float* be2 = (const float*)d_in[11];
    const float* g3  = (const float*)d_in[12];
    const float* be3 = (const float*)d_in[13];
    const float* Wf  = (const float*)d_in[14];
    const float* bf  = (const float*)d_in[15];
    float* out = (float*)d_out;

    char* ws = (char*)d_ws;
    size_t off = 0;
    auto alloc = [&](size_t bytes) -> void* {
        void* p = ws + off;
        off = (off + bytes + 255) & ~(size_t)255;
        return p;
    };
    int*   cntp  = (int*)alloc((size_t)N_NODES * 16 * 4);    // 64B-padded counters, 3.2MB
    int*   adj   = (int*)alloc((size_t)N_NODES * CAP * 4);   // 12.8 MB padded rows
    int*   cnt   = (int*)alloc((size_t)N_NODES * 4);
    float* dinv  = (float*)alloc((size_t)N_NODES * 4);
    float* sums  = (float*)alloc((size_t)3 * NCOPY * 256 * 4);  // shadow-copied stats
    float* st    = (float*)alloc((size_t)3 * 256 * 4);          // precomputed BN scale/shift
    unsigned short* WT   = (unsigned short*)alloc((size_t)3 * 128 * 128 * 2);
    unsigned short* WfT  = (unsigned short*)alloc((size_t)3 * 16 * 128 * 2);
    unsigned short* hl   = (unsigned short*)alloc((size_t)N_NODES * 128 * 2);  // bf16
    unsigned short* bufA = (unsigned short*)alloc((size_t)N_NODES * 128 * 2);  // bf16 agg
    unsigned short* bufB = (unsigned short*)alloc((size_t)N_NODES * 128 * 2);  // bf16 agg

    const int TPB = 256;
    const int SL = NCOPY * 256;   // per-layer sums stride
    k_setup<<<412, 256, 0, stream>>>(W1, W2, W3, Wf, WT, WfT, cntp, sums);

    // ---- layer 1 GEMM fused with direct adjacency build (gemm tiles FIRST) ----
    k_gemm<<<GEMM_GRID + LINKB, 128, 0, stream>>>(
        x, nullptr, WT, hl, nullptr, nullptr,
        nullptr, nullptr, 0, nullptr, ei, cntp, adj);
    k_dinv<<<(N_NODES + TPB - 1) / TPB, TPB, 0, stream>>>(cntp, cnt, dinv);
    k_agg<<<AGG_BLOCKS, 256, 0, stream>>>(hl, adj, cnt, dinv, bufA, sums + 0, 0);
    k_bnfin<<<1, 128, 0, stream>>>(sums + 0, g1, be1, st + 0);

    // ---- layer 2 (gemm also emits out = h1 @ Wf0 + bf; hl pre-scaled by dinv) ----
    k_gemm<<<GEMM_GRID, 128, 0, stream>>>(nullptr, bufA, WT + 16384, hl, st + 0,
                                          WfT, bf, out, 1, dinv, nullptr, nullptr, nullptr);
    k_agg<<<AGG_BLOCKS, 256, 0, stream>>>(hl, adj, cnt, dinv, bufB, sums + SL, 1);
    k_bnfin<<<1, 128, 0, stream>>>(sums + SL, g2, be2, st + 256);

    // ---- layer 3 (gemm also emits out += h2 @ Wf1; hl pre-scaled by dinv) ----
    k_gemm<<<GEMM_GRID, 128, 0, stream>>>(nullptr, bufB, WT + 32768, hl, st + 256,
                                          WfT + 2048, nullptr, out, 2, dinv,
                                          nullptr, nullptr, nullptr);
    k_agg<<<AGG_BLOCKS, 256, 0, stream>>>(hl, adj, cnt, dinv, bufA, sums + 2 * SL, 1);
    k_bnfin<<<1, 128, 0, stream>>>(sums + 2 * SL, g3, be3, st + 512);

    // ---- layer 3 readout (MFMA) ----
    k_out_mfma<<<GEMM_GRID, 128, 0, stream>>>(bufA, WfT + 4096, out, st + 512);
}

// Round 9
// 333.058 us; speedup vs baseline: 1.2737x; 1.1937x over previous
//
#include <hip/hip_runtime.h>

#define N_NODES 50000
#define N_EDGES 800000
#define D 128
#define C_OUT 10
#define BN_EPS 1e-5f
#define CAP 64            // padded adjacency row capacity; P(deg>=63)~1e-17 (Poisson 16)
#define MTILE 16          // R18: 16-row x 128-thr tiles, 2 waves split N -> 3125 blocks,
                          // ~24 waves/CU (R15/R6 showed tile-halving is the occupancy lever)
#define GEMM_GRID 3125    // 50000/16 exactly
#define OTILE 32          // out_mfma keeps 32-row tiles (readout-only kernel)
#define OUT_GRID 1563     // ceil(50000/32)
#define LINKB 782         // link blocks appended AFTER gemm tiles; 782*128*8 >= E
#define AGG_BLOCKS 2048   // 8 blocks/CU resident; whole grid co-resident
#define NCOPY 32          // BN-stats shadow copies (R13)
#define CSTR 136          // LDS C-dump row stride (ushorts): quad writes 2-way max

// R17: last-block-ticket bnfin fusion REVERTED (single-address value-returning atomics).
// R18: k_agg split into k_agg0/k_agg1 — the runtime `scaled` branch in R7/R8's unified
// kernel perturbed the gather-loop codegen (~+20us on EVERY agg; layer-1 agg 57->78us
// with identical FETCH/WRITE). Compile-time variants restore the R6 interleaved loop.

typedef unsigned int uint32;
typedef __attribute__((ext_vector_type(8))) short bf16x8;
typedef __attribute__((ext_vector_type(4))) float f32x4;

__device__ __forceinline__ float bf2f(unsigned int u16) {
    unsigned int x = u16 << 16;
    float f;
    __builtin_memcpy(&f, &x, 4);
    return f;
}
__device__ __forceinline__ unsigned int f2bf(float f) {
    unsigned int x;
    __builtin_memcpy(&x, &f, 4);
    unsigned int r = x + 0x7FFFu + ((x >> 16) & 1u);  // RNE
    return r >> 16;
}
__device__ __forceinline__ uint32 pack_bf2(float a, float b) {
    return f2bf(a) | (f2bf(b) << 16);
}

// ---------------- setup: W^T bf16, Wf^T bf16, cntp=0 (64B-padded), sums=0 ----------

__global__ void k_setup(const float* __restrict__ W1, const float* __restrict__ W2,
                        const float* __restrict__ W3, const float* __restrict__ Wf,
                        unsigned short* __restrict__ WT, unsigned short* __restrict__ WfT,
                        int* __restrict__ cntp, float* __restrict__ sums) {
    int b = blockIdx.x, tid = threadIdx.x;
    if (b < 192) {                       // WT: 3 x 128 x 128
        int idx = b * 256 + tid;
        int mat = idx >> 14, rem = idx & 16383;
        int n = rem >> 7, k = rem & 127;
        const float* W = (mat == 0) ? W1 : ((mat == 1) ? W2 : W3);
        WT[idx] = (unsigned short)f2bf(W[k * 128 + n]);
    } else if (b < 216) {                // WfT: 3 slices x 16(n,pad) x 128(k)
        int idx = (b - 192) * 256 + tid;
        if (idx < 6144) {
            int li = idx >> 11, rem = idx & 2047;
            int n = rem >> 7, k = rem & 127;
            WfT[idx] = (n < C_OUT) ? (unsigned short)f2bf(Wf[(li * 128 + k) * C_OUT + n]) : 0;
        }
    } else {                             // per-node atomic counter init + sums zero
        int i = (b - 216) * 256 + tid;
        if (i < N_NODES) cntp[i << 4] = 0;   // one counter per 64B line (atomic de-contention)
        if (i < 3 * NCOPY * 256) sums[i] = 0.0f;
    }
}

// ---------------- compact deg: cnt (stored edges) + dinv = rsqrt(deg+1) ----------

__global__ void k_dinv(const int* __restrict__ cntp, int* __restrict__ cnt,
                       float* __restrict__ dinv) {
    int i = blockIdx.x * blockDim.x + threadIdx.x;
    if (i >= N_NODES) return;
    int c = cntp[i << 4];                        // in-edges (excl self)
    cnt[i] = (c < CAP) ? c : CAP;                // stored slots
    dinv[i] = rsqrtf((float)(c + 1));            // exact deg incl self (matches ref)
}

// ---------------- BN finalize: reduce NCOPY shadow copies -> scale/shift st[2][128] ----

__global__ void k_bnfin(const float* __restrict__ sums, const float* __restrict__ g,
                        const float* __restrict__ be, float* __restrict__ st) {
    int t = threadIdx.x;      // 128 threads
    float sm = 0.f, sq = 0.f;
    for (int c = 0; c < NCOPY; ++c) {
        sm += sums[c * 256 + t];
        sq += sums[c * 256 + 128 + t];
    }
    float mean = sm * (1.0f / N_NODES);
    float var = fmaxf(sq * (1.0f / N_NODES) - mean * mean, 0.f);
    float s = g[t] * rsqrtf(var + BN_EPS);
    st[t] = s;
    st[128 + t] = be[t] - mean * s;
}

// ---------------- MFMA GEMM (+ optional fused adjacency build, BN prologue, readout)
// R18: 16-row tiles, 128 threads = 2 waves; wave w computes output cols [w*64, w*64+64).
// hl[M,128](bf16) = bnrelu(A) @ W; if dinvp: rows pre-scaled by dinv (R16).
// A: Af32 (layer1) XOR Abf (bf16, BN'd via st). W read DIRECTLY from global WT (R14).
// C-tile: acc -> LDS (stride CSTR) -> coalesced uint4 store (R10).
// If linkEi: blocks [GEMM_GRID, GEMM_GRID+LINKB) do the direct slot build.
// mode: 0=none, 1=out = staged@WfT + bias, 2=out += staged@WfT (wave 0 only).

__global__ __launch_bounds__(128) void k_gemm(const float* __restrict__ Af32,
                                              const unsigned short* __restrict__ Abf,
                                              const unsigned short* __restrict__ WT,
                                              unsigned short* __restrict__ hl,
                                              const float* __restrict__ st,
                                              const unsigned short* __restrict__ WfT,
                                              const float* __restrict__ bfv,
                                              float* __restrict__ outp, int mode,
                                              const float* __restrict__ dinvp,
                                              const int* __restrict__ linkEi,
                                              int* __restrict__ cntp,
                                              int* __restrict__ adj) {
    __shared__ unsigned short SM[MTILE * CSTR];   // 4.3 KB
    unsigned short* As = SM;
    int tid = threadIdx.x;
    int bid = blockIdx.x;

    if (linkEi && bid >= GEMM_GRID) {
        // direct adjacency build: 8 edges/thread, independent atomics (ILP)
        int lb = bid - GEMM_GRID;
        int d8[8], s8[8];
#pragma unroll
        for (int u = 0; u < 8; ++u) {
            int e = (lb * 8 + u) * 128 + tid;
            d8[u] = (e < N_EDGES) ? linkEi[N_EDGES + e] : -1;   // destination
            s8[u] = (e < N_EDGES) ? linkEi[e] : 0;              // source
        }
#pragma unroll
        for (int u = 0; u < 8; ++u) {
            if (d8[u] >= 0) {
                int slot = atomicAdd(&cntp[d8[u] << 4], 1);
                if (slot < CAP) adj[(d8[u] << 6) + slot] = s8[u];
            }
        }
        return;
    }
    int row0 = bid * MTILE;

    if (Abf) {
        // bf16 A path: thread stages 2 rows of its fixed column octet (c8 = tid&15)
        int c8 = tid & 15, cc = c8 * 8;
        float s8[8], t8[8];
        {
            float4 a0 = *(const float4*)&st[cc];
            float4 a1 = *(const float4*)&st[cc + 4];
            float4 b0 = *(const float4*)&st[128 + cc];
            float4 b1 = *(const float4*)&st[128 + cc + 4];
            s8[0] = a0.x; s8[1] = a0.y; s8[2] = a0.z; s8[3] = a0.w;
            s8[4] = a1.x; s8[5] = a1.y; s8[6] = a1.z; s8[7] = a1.w;
            t8[0] = b0.x; t8[1] = b0.y; t8[2] = b0.z; t8[3] = b0.w;
            t8[4] = b1.x; t8[5] = b1.y; t8[6] = b1.z; t8[7] = b1.w;
        }
        const uint4* H4 = (const uint4*)Abf;
#pragma unroll
        for (int i = 0; i < 2; ++i) {
            int r = i * 8 + (tid >> 4);         // 0..15
            int gr = row0 + r;
            uint4 v = make_uint4(0, 0, 0, 0);
            if (gr < N_NODES) v = H4[(size_t)gr * 16 + c8];
            uint32 w[4] = {v.x, v.y, v.z, v.w};
            uint32 o[4];
#pragma unroll
            for (int p = 0; p < 4; ++p) {
                float f0 = bf2f(w[p] & 0xFFFFu) * s8[2 * p] + t8[2 * p];
                float f1 = bf2f(w[p] >> 16) * s8[2 * p + 1] + t8[2 * p + 1];
                o[p] = pack_bf2(fmaxf(f0, 0.f), fmaxf(f1, 0.f));
            }
            int swz = c8 ^ (r & 15);
            *(uint4*)&As[r * 128 + swz * 8] = make_uint4(o[0], o[1], o[2], o[3]);
        }
    } else {
        // fp32 A path (layer 1: x, no BN)
        const float4* A4 = (const float4*)Af32;
        int c4 = tid & 31;
#pragma unroll
        for (int i = 0; i < 4; ++i) {
            int r = i * 4 + (tid >> 5);         // 0..15
            int gr = row0 + r;
            float4 v = make_float4(0.f, 0.f, 0.f, 0.f);
            if (gr < N_NODES) v = A4[(size_t)gr * 32 + c4];
            ushort4 o;
            o.x = (unsigned short)f2bf(v.x);
            o.y = (unsigned short)f2bf(v.y);
            o.z = (unsigned short)f2bf(v.z);
            o.w = (unsigned short)f2bf(v.w);
            int swz = (c4 >> 1) ^ (r & 15);
            *(ushort4*)&As[r * 128 + swz * 8 + (c4 & 1) * 4] = o;
        }
    }
    __syncthreads();

    int wave = tid >> 6, lane = tid & 63;
    int quad = lane >> 4, l16 = lane & 15;
    int m = l16;

    // a-frags: A[m][k = ks*32 + quad*8 + j] (same for both waves)
    bf16x8 af[4];
#pragma unroll
    for (int ks = 0; ks < 4; ++ks) {
        int swz = (ks * 4 + quad) ^ l16;
        af[ks] = *(bf16x8*)&As[m * 128 + swz * 8];
    }

    f32x4 acc[4];
#pragma unroll
    for (int nt = 0; nt < 4; ++nt) acc[nt] = (f32x4){0.f, 0.f, 0.f, 0.f};

#pragma unroll
    for (int nt = 0; nt < 4; ++nt) {
        int n = (wave * 4 + nt) * 16 + l16;
        bf16x8 bfr[4];
#pragma unroll
        for (int ks = 0; ks < 4; ++ks)
            bfr[ks] = *(const bf16x8*)&WT[n * 128 + (ks * 4 + quad) * 8];  // global, L2-hot
#pragma unroll
        for (int ks = 0; ks < 4; ++ks)
            acc[nt] = __builtin_amdgcn_mfma_f32_16x16x32_bf16(af[ks], bfr[ks], acc[nt], 0, 0, 0);
    }

    // fused readout partial (wave 0 only — mode 2 += must not double-add)
    if (mode != 0 && wave == 0) {
        f32x4 accO = (f32x4){0.f, 0.f, 0.f, 0.f};
#pragma unroll
        for (int ks = 0; ks < 4; ++ks) {
            bf16x8 bw = *(const bf16x8*)&WfT[l16 * 128 + (ks * 4 + quad) * 8];  // tiny, L2-hot
            accO = __builtin_amdgcn_mfma_f32_16x16x32_bf16(af[ks], bw, accO, 0, 0, 0);
        }
        if (l16 < C_OUT) {
#pragma unroll
            for (int reg = 0; reg < 4; ++reg) {
                int gm = row0 + quad * 4 + reg;
                if (gm < N_NODES) {
                    size_t o = (size_t)gm * C_OUT + l16;
                    float v = accO[reg];
                    if (mode == 1) outp[o] = v + bfv[l16];
                    else outp[o] += v;
                }
            }
        }
    }

    // optional dinv pre-scale factors for this thread's 4 output rows (R16)
    float dv[4] = {1.f, 1.f, 1.f, 1.f};
    if (dinvp) {
#pragma unroll
        for (int reg = 0; reg < 4; ++reg) {
            int gm = row0 + quad * 4 + reg;
            dv[reg] = (gm < N_NODES) ? dinvp[gm] : 0.f;
        }
    }

    // C-tile: acc -> LDS (bf16, stride CSTR) -> coalesced uint4 stores (full lines)
    __syncthreads();   // all waves done reading As
#pragma unroll
    for (int reg = 0; reg < 4; ++reg) {
        int lm = quad * 4 + reg;         // local row 0..15
#pragma unroll
        for (int nt = 0; nt < 4; ++nt)
            SM[lm * CSTR + (wave * 4 + nt) * 16 + l16] =
                (unsigned short)f2bf(acc[nt][reg] * dv[reg]);
    }
    __syncthreads();
    uint4* H4o = (uint4*)hl;
#pragma unroll
    for (int i = 0; i < 2; ++i) {
        int r = i * 8 + (tid >> 4), c8 = tid & 15;
        int gr = row0 + r;
        if (gr < N_NODES)
            H4o[(size_t)gr * 16 + c8] = *(uint4*)&SM[r * CSTR + c8 * 8];
    }
}

// ---------------- Aggregation, layer 1 (UNSCALED hl): R6-exact interleaved inner loop.
// wave/node grid-stride, unroll-8, per-edge dinv, bf16 out, fused BN stats.

__global__ __launch_bounds__(256) void k_agg0(const unsigned short* __restrict__ hl,
                                              const int* __restrict__ adj,
                                              const int* __restrict__ cnt,
                                              const float* __restrict__ dinv,
                                              unsigned short* __restrict__ agg,
                                              float* __restrict__ sums) {
    __shared__ float red[4][256];
    int tid = threadIdx.x;
    int lane = tid & 63;
    int gw = (blockIdx.x << 2) | (tid >> 6);      // global wave id
    float sx = 0.f, qx = 0.f, sy = 0.f, qy = 0.f;

    for (int node = gw; node < N_NODES; node += AGG_BLOCKS * 4) {
        const int* row = adj + ((size_t)node << 6);   // wave-uniform scalar reads
        int n = cnt[node];
        float di = dinv[node];
        uint32 ps = *(const uint32*)&hl[(size_t)node * 128 + lane * 2];
        float ax = bf2f(ps & 0xFFFFu) * di;           // self-loop seed
        float ay = bf2f(ps >> 16) * di;
        int e = 0;
        for (; e + 7 < n; e += 8) {
            int j[8];
#pragma unroll
            for (int u = 0; u < 8; ++u) j[u] = row[e + u];
            float w[8];
            uint32 p[8];
#pragma unroll
            for (int u = 0; u < 8; ++u) {
                w[u] = dinv[j[u]];
                p[u] = *(const uint32*)&hl[(size_t)j[u] * 128 + lane * 2];
            }
#pragma unroll
            for (int u = 0; u < 8; ++u) {
                ax += bf2f(p[u] & 0xFFFFu) * w[u];
                ay += bf2f(p[u] >> 16) * w[u];
            }
        }
        for (; e < n; ++e) {
            int j = row[e];
            float w = dinv[j];
            uint32 p = *(const uint32*)&hl[(size_t)j * 128 + lane * 2];
            ax += bf2f(p & 0xFFFFu) * w;
            ay += bf2f(p >> 16) * w;
        }
        float ox = ax * di, oy = ay * di;
        *(uint32*)&agg[(size_t)node * 128 + lane * 2] = pack_bf2(ox, oy);
        sx += ox; qx += ox * ox; sy += oy; qy += oy * oy;
    }

    red[0][tid] = sx; red[1][tid] = qx; red[2][tid] = sy; red[3][tid] = qy;
    __syncthreads();
    int s = tid >> 6, l = tid & 63;
    float v = red[s][l] + red[s][64 + l] + red[s][128 + l] + red[s][192 + l];
    atomicAdd(&sums[((blockIdx.x & (NCOPY - 1)) << 8) + (s & 1) * 128 + 2 * l + (s >> 1)], v);
}

// ---------------- Aggregation, layers 2/3 (hl pre-scaled by dinv in gemm C-store):
// no per-edge dinv gather at all. Same stats epilogue.

__global__ __launch_bounds__(256) void k_agg1(const unsigned short* __restrict__ hl,
                                              const int* __restrict__ adj,
                                              const int* __restrict__ cnt,
                                              const float* __restrict__ dinv,
                                              unsigned short* __restrict__ agg,
                                              float* __restrict__ sums) {
    __shared__ float red[4][256];
    int tid = threadIdx.x;
    int lane = tid & 63;
    int gw = (blockIdx.x << 2) | (tid >> 6);      // global wave id
    float sx = 0.f, qx = 0.f, sy = 0.f, qy = 0.f;

    for (int node = gw; node < N_NODES; node += AGG_BLOCKS * 4) {
        const int* row = adj + ((size_t)node << 6);   // wave-uniform scalar reads
        int n = cnt[node];
        float di = dinv[node];
        uint32 ps = *(const uint32*)&hl[(size_t)node * 128 + lane * 2];
        float ax = bf2f(ps & 0xFFFFu);                // self term already dinv-scaled
        float ay = bf2f(ps >> 16);
        int e = 0;
        for (; e + 7 < n; e += 8) {
            int j[8];
#pragma unroll
            for (int u = 0; u < 8; ++u) j[u] = row[e + u];
            uint32 p[8];
#pragma unroll
            for (int u = 0; u < 8; ++u)
                p[u] = *(const uint32*)&hl[(size_t)j[u] * 128 + lane * 2];
#pragma unroll
            for (int u = 0; u < 8; ++u) {
                ax += bf2f(p[u] & 0xFFFFu);
                ay += bf2f(p[u] >> 16);
            }
        }
        for (; e < n; ++e) {
            int j = row[e];
            uint32 p = *(const uint32*)&hl[(size_t)j * 128 + lane * 2];
            ax += bf2f(p & 0xFFFFu);
            ay += bf2f(p >> 16);
        }
        float ox = ax * di, oy = ay * di;
        *(uint32*)&agg[(size_t)node * 128 + lane * 2] = pack_bf2(ox, oy);
        sx += ox; qx += ox * ox; sy += oy; qy += oy * oy;
    }

    red[0][tid] = sx; red[1][tid] = qx; red[2][tid] = sy; red[3][tid] = qy;
    __syncthreads();
    int s = tid >> 6, l = tid & 63;
    float v = red[s][l] + red[s][64 + l] + red[s][128 + l] + red[s][192 + l];
    atomicAdd(&sums[((blockIdx.x & (NCOPY - 1)) << 8) + (s & 1) * 128 + 2 * l + (s >> 1)], v);
}

// ---------------- Layer-3 readout: MFMA, out += bnrelu(h3) @ WfT-slice2 (32-row tiles) ----

__global__ __launch_bounds__(128) void k_out_mfma(const unsigned short* __restrict__ h,
                                                  const unsigned short* __restrict__ WfT,
                                                  float* __restrict__ outp,
                                                  const float* __restrict__ st) {
    __shared__ unsigned short As[OTILE * 128];  // 8 KB
    int tid = threadIdx.x;
    int row0 = blockIdx.x * OTILE;

    int c8 = tid & 15, cc = c8 * 8;
    float s8[8], t8[8];
    {
        float4 a0 = *(const float4*)&st[cc];
        float4 a1 = *(const float4*)&st[cc + 4];
        float4 b0 = *(const float4*)&st[128 + cc];
        float4 b1 = *(const float4*)&st[128 + cc + 4];
        s8[0] = a0.x; s8[1] = a0.y; s8[2] = a0.z; s8[3] = a0.w;
        s8[4] = a1.x; s8[5] = a1.y; s8[6] = a1.z; s8[7] = a1.w;
        t8[0] = b0.x; t8[1] = b0.y; t8[2] = b0.z; t8[3] = b0.w;
        t8[4] = b1.x; t8[5] = b1.y; t8[6] = b1.z; t8[7] = b1.w;
    }
    const uint4* H4 = (const uint4*)h;
#pragma unroll
    for (int i = 0; i < 4; ++i) {
        int idx = i * 128 + tid;
        int r = idx >> 4;
        int gr = row0 + r;
        uint4 v = make_uint4(0, 0, 0, 0);
        if (gr < N_NODES) v = H4[(size_t)gr * 16 + c8];
        uint32 w[4] = {v.x, v.y, v.z, v.w};
        uint32 o[4];
#pragma unroll
        for (int p = 0; p < 4; ++p) {
            float f0 = bf2f(w[p] & 0xFFFFu) * s8[2 * p] + t8[2 * p];
            float f1 = bf2f(w[p] >> 16) * s8[2 * p + 1] + t8[2 * p + 1];
            o[p] = pack_bf2(fmaxf(f0, 0.f), fmaxf(f1, 0.f));
        }
        int swz = c8 ^ (r & 15);
        *(uint4*)&As[r * 128 + swz * 8] = make_uint4(o[0], o[1], o[2], o[3]);
    }
    __syncthreads();

    int wave = tid >> 6, lane = tid & 63;
    int quad = lane >> 4, l16 = lane & 15;
    int m0 = wave * 16;
    int m = m0 + l16;

    f32x4 accO = (f32x4){0.f, 0.f, 0.f, 0.f};
#pragma unroll
    for (int ks = 0; ks < 4; ++ks) {
        bf16x8 bw = *(const bf16x8*)&WfT[l16 * 128 + (ks * 4 + quad) * 8];
        int swz = (ks * 4 + quad) ^ (m & 15);
        bf16x8 av = *(bf16x8*)&As[m * 128 + swz * 8];
        accO = __builtin_amdgcn_mfma_f32_16x16x32_bf16(av, bw, accO, 0, 0, 0);
    }
    if (l16 < C_OUT) {
#pragma unroll
        for (int reg = 0; reg < 4; ++reg) {
            int gm = row0 + m0 + quad * 4 + reg;
            if (gm < N_NODES)
                outp[(size_t)gm * C_OUT + l16] += accO[reg];
        }
    }
}

// ---------------- launch ----------------

extern "C" void kernel_launch(void* const* d_in, const int* in_sizes, int n_in,
                              void* d_out, int out_size, void* d_ws, size_t ws_size,
                              hipStream_t stream) {
    const float* x  = (const float*)d_in[0];
    const int*   ei = (const int*)d_in[1];
    const float* W1 = (const float*)d_in[2];
    const float* W2 = (const float*)d_in[4];
    const float* W3 = (const float*)d_in[6];
    // b1/b2/b3 absorbed exactly by BN mean-subtraction
    const float* g1  = (const float*)d_in[8];
    const float* be1 = (const float*)d_in[9];
    const float* g2  = (const float*)d_in[10];
    const float* be2 = (const float*)d_in[11];
    const float* g3  = (const float*)d_in[12];
    const float* be3 = (const float*)d_in[13];
    const float* Wf  = (const float*)d_in[14];
    const float* bf  = (const float*)d_in[15];
    float* out = (float*)d_out;

    char* ws = (char*)d_ws;
    size_t off = 0;
    auto alloc = [&](size_t bytes) -> void* {
        void* p = ws + off;
        off = (off + bytes + 255) & ~(size_t)255;
        return p;
    };
    int*   cntp  = (int*)alloc((size_t)N_NODES * 16 * 4);    // 64B-padded counters, 3.2MB
    int*   adj   = (int*)alloc((size_t)N_NODES * CAP * 4);   // 12.8 MB padded rows
    int*   cnt   = (int*)alloc((size_t)N_NODES * 4);
    float* dinv  = (float*)alloc((size_t)N_NODES * 4);
    float* sums  = (float*)alloc((size_t)3 * NCOPY * 256 * 4);  // shadow-copied stats
    float* st    = (float*)alloc((size_t)3 * 256 * 4);          // precomputed BN scale/shift
    unsigned short* WT   = (unsigned short*)alloc((size_t)3 * 128 * 128 * 2);
    unsigned short* WfT  = (unsigned short*)alloc((size_t)3 * 16 * 128 * 2);
    unsigned short* hl   = (unsigned short*)alloc((size_t)N_NODES * 128 * 2);  // bf16
    unsigned short* bufA = (unsigned short*)alloc((size_t)N_NODES * 128 * 2);  // bf16 agg
    unsigned short* bufB = (unsigned short*)alloc((size_t)N_NODES * 128 * 2);  // bf16 agg

    const int TPB = 256;
    const int SL = NCOPY * 256;   // per-layer sums stride
    k_setup<<<412, 256, 0, stream>>>(W1, W2, W3, Wf, WT, WfT, cntp, sums);

    // ---- layer 1 GEMM fused with direct adjacency build (gemm tiles FIRST) ----
    k_gemm<<<GEMM_GRID + LINKB, 128, 0, stream>>>(
        x, nullptr, WT, hl, nullptr, nullptr,
        nullptr, nullptr, 0, nullptr, ei, cntp, adj);
    k_dinv<<<(N_NODES + TPB - 1) / TPB, TPB, 0, stream>>>(cntp, cnt, dinv);
    k_agg0<<<AGG_BLOCKS, 256, 0, stream>>>(hl, adj, cnt, dinv, bufA, sums + 0);
    k_bnfin<<<1, 128, 0, stream>>>(sums + 0, g1, be1, st + 0);

    // ---- layer 2 (gemm also emits out = h1 @ Wf0 + bf; hl pre-scaled by dinv) ----
    k_gemm<<<GEMM_GRID, 128, 0, stream>>>(nullptr, bufA, WT + 16384, hl, st + 0,
                                          WfT, bf, out, 1, dinv, nullptr, nullptr, nullptr);
    k_agg1<<<AGG_BLOCKS, 256, 0, stream>>>(hl, adj, cnt, dinv, bufB, sums + SL);
    k_bnfin<<<1, 128, 0, stream>>>(sums + SL, g2, be2, st + 256);

    // ---- layer 3 (gemm also emits out += h2 @ Wf1; hl pre-scaled by dinv) ----
    k_gemm<<<GEMM_GRID, 128, 0, stream>>>(nullptr, bufB, WT + 32768, hl, st + 256,
                                          WfT + 2048, nullptr, out, 2, dinv,
                                          nullptr, nullptr, nullptr);
    k_agg1<<<AGG_BLOCKS, 256, 0, stream>>>(hl, adj, cnt, dinv, bufA, sums + 2 * SL);
    k_bnfin<<<1, 128, 0, stream>>>(sums + 2 * SL, g3, be3, st + 512);

    // ---- layer 3 readout (MFMA) ----
    k_out_mfma<<<OUT_GRID, 128, 0, stream>>>(bufA, WfT + 4096, out, st + 512);
}

// Round 10
// 326.707 us; speedup vs baseline: 1.2985x; 1.0194x over previous
//
#include <hip/hip_runtime.h>

#define N_NODES 50000
#define N_EDGES 800000
#define D 128
#define C_OUT 10
#define BN_EPS 1e-5f
#define CAP 64            // padded adjacency row capacity; P(deg>=63)~1e-17 (Poisson 16)
#define MTILE 32          // R19: revert R18's MTILE=16 — fixed per-block overhead made
                          // 2x blocks slower (fused 58.7->78.4us, occ 40->27%); 32 is the knee
#define GEMM_GRID 1563    // ceil(50000/32)
#define OTILE 32          // out_mfma 32-row tiles
#define OUT_GRID 1563     // ceil(50000/32)
#define LINKB 782         // link blocks appended AFTER gemm tiles; 782*128*8 >= E
#define AGG_BLOCKS 2048   // 8 blocks/CU resident; whole grid co-resident
#define NCOPY 32          // BN-stats shadow copies (R13)
#define CSTR 136          // LDS C-dump row stride (ushorts): quad writes 2-way max

// R17: last-block-ticket bnfin fusion REVERTED (single-address value-returning atomics).
// R18: k_agg split into k_agg0/k_agg1 — runtime `scaled` branch perturbed gather codegen
// (~+20us on every agg). Compile-time variants keep the R6 interleaved loop. KEPT.
// R16: gemm2/3 C-store pre-scales rows by dinv so k_agg1 skips per-edge dinv. KEPT.

typedef unsigned int uint32;
typedef __attribute__((ext_vector_type(8))) short bf16x8;
typedef __attribute__((ext_vector_type(4))) float f32x4;

__device__ __forceinline__ float bf2f(unsigned int u16) {
    unsigned int x = u16 << 16;
    float f;
    __builtin_memcpy(&f, &x, 4);
    return f;
}
__device__ __forceinline__ unsigned int f2bf(float f) {
    unsigned int x;
    __builtin_memcpy(&x, &f, 4);
    unsigned int r = x + 0x7FFFu + ((x >> 16) & 1u);  // RNE
    return r >> 16;
}
__device__ __forceinline__ uint32 pack_bf2(float a, float b) {
    return f2bf(a) | (f2bf(b) << 16);
}

// ---------------- setup: W^T bf16, Wf^T bf16, cntp=0 (64B-padded), sums=0 ----------

__global__ void k_setup(const float* __restrict__ W1, const float* __restrict__ W2,
                        const float* __restrict__ W3, const float* __restrict__ Wf,
                        unsigned short* __restrict__ WT, unsigned short* __restrict__ WfT,
                        int* __restrict__ cntp, float* __restrict__ sums) {
    int b = blockIdx.x, tid = threadIdx.x;
    if (b < 192) {                       // WT: 3 x 128 x 128
        int idx = b * 256 + tid;
        int mat = idx >> 14, rem = idx & 16383;
        int n = rem >> 7, k = rem & 127;
        const float* W = (mat == 0) ? W1 : ((mat == 1) ? W2 : W3);
        WT[idx] = (unsigned short)f2bf(W[k * 128 + n]);
    } else if (b < 216) {                // WfT: 3 slices x 16(n,pad) x 128(k)
        int idx = (b - 192) * 256 + tid;
        if (idx < 6144) {
            int li = idx >> 11, rem = idx & 2047;
            int n = rem >> 7, k = rem & 127;
            WfT[idx] = (n < C_OUT) ? (unsigned short)f2bf(Wf[(li * 128 + k) * C_OUT + n]) : 0;
        }
    } else {                             // per-node atomic counter init + sums zero
        int i = (b - 216) * 256 + tid;
        if (i < N_NODES) cntp[i << 4] = 0;   // one counter per 64B line (atomic de-contention)
        if (i < 3 * NCOPY * 256) sums[i] = 0.0f;
    }
}

// ---------------- compact deg: cnt (stored edges) + dinv = rsqrt(deg+1) ----------

__global__ void k_dinv(const int* __restrict__ cntp, int* __restrict__ cnt,
                       float* __restrict__ dinv) {
    int i = blockIdx.x * blockDim.x + threadIdx.x;
    if (i >= N_NODES) return;
    int c = cntp[i << 4];                        // in-edges (excl self)
    cnt[i] = (c < CAP) ? c : CAP;                // stored slots
    dinv[i] = rsqrtf((float)(c + 1));            // exact deg incl self (matches ref)
}

// ---------------- BN finalize: reduce NCOPY shadow copies -> scale/shift st[2][128] ----

__global__ void k_bnfin(const float* __restrict__ sums, const float* __restrict__ g,
                        const float* __restrict__ be, float* __restrict__ st) {
    int t = threadIdx.x;      // 128 threads
    float sm = 0.f, sq = 0.f;
    for (int c = 0; c < NCOPY; ++c) {
        sm += sums[c * 256 + t];
        sq += sums[c * 256 + 128 + t];
    }
    float mean = sm * (1.0f / N_NODES);
    float var = fmaxf(sq * (1.0f / N_NODES) - mean * mean, 0.f);
    float s = g[t] * rsqrtf(var + BN_EPS);
    st[t] = s;
    st[128 + t] = be[t] - mean * s;
}

// ---------------- MFMA GEMM (+ optional fused adjacency build, BN prologue, readout)
// 32-row tiles, 128 threads = 2 waves; wave w owns rows [w*16, w*16+16) x all 128 cols.
// hl[M,128](bf16) = bnrelu(A) @ W; if dinvp: rows pre-scaled by dinv (R16).
// A: Af32 (layer1) XOR Abf (bf16, BN'd via st). W read DIRECTLY from global WT (R14).
// C-tile: acc -> LDS (stride CSTR) -> coalesced uint4 store (R10).
// If linkEi: blocks [GEMM_GRID, GEMM_GRID+LINKB) do the direct slot build.
// mode: 0=none, 1=out = staged@WfT + bias, 2=out += staged@WfT.

__global__ __launch_bounds__(128) void k_gemm(const float* __restrict__ Af32,
                                              const unsigned short* __restrict__ Abf,
                                              const unsigned short* __restrict__ WT,
                                              unsigned short* __restrict__ hl,
                                              const float* __restrict__ st,
                                              const unsigned short* __restrict__ WfT,
                                              const float* __restrict__ bfv,
                                              float* __restrict__ outp, int mode,
                                              const float* __restrict__ dinvp,
                                              const int* __restrict__ linkEi,
                                              int* __restrict__ cntp,
                                              int* __restrict__ adj) {
    __shared__ unsigned short SM[MTILE * CSTR];   // 8.7 KB
    unsigned short* As = SM;
    int tid = threadIdx.x;
    int bid = blockIdx.x;

    if (linkEi && bid >= GEMM_GRID) {
        // direct adjacency build: 8 edges/thread, independent atomics (ILP)
        int lb = bid - GEMM_GRID;
        int d8[8], s8[8];
#pragma unroll
        for (int u = 0; u < 8; ++u) {
            int e = (lb * 8 + u) * 128 + tid;
            d8[u] = (e < N_EDGES) ? linkEi[N_EDGES + e] : -1;   // destination
            s8[u] = (e < N_EDGES) ? linkEi[e] : 0;              // source
        }
#pragma unroll
        for (int u = 0; u < 8; ++u) {
            if (d8[u] >= 0) {
                int slot = atomicAdd(&cntp[d8[u] << 4], 1);
                if (slot < CAP) adj[(d8[u] << 6) + slot] = s8[u];
            }
        }
        return;
    }
    int row0 = bid * MTILE;

    if (Abf) {
        // bf16 A path: thread stages 2 rows of its fixed column octet (c8 = tid&15)
        int c8 = tid & 15, cc = c8 * 8;
        float s8[8], t8[8];
        {
            float4 a0 = *(const float4*)&st[cc];
            float4 a1 = *(const float4*)&st[cc + 4];
            float4 b0 = *(const float4*)&st[128 + cc];
            float4 b1 = *(const float4*)&st[128 + cc + 4];
            s8[0] = a0.x; s8[1] = a0.y; s8[2] = a0.z; s8[3] = a0.w;
            s8[4] = a1.x; s8[5] = a1.y; s8[6] = a1.z; s8[7] = a1.w;
            t8[0] = b0.x; t8[1] = b0.y; t8[2] = b0.z; t8[3] = b0.w;
            t8[4] = b1.x; t8[5] = b1.y; t8[6] = b1.z; t8[7] = b1.w;
        }
        const uint4* H4 = (const uint4*)Abf;
#pragma unroll
        for (int i = 0; i < 4; ++i) {
            int idx = i * 128 + tid;
            int r = idx >> 4;                   // 0..31
            int gr = row0 + r;
            uint4 v = make_uint4(0, 0, 0, 0);
            if (gr < N_NODES) v = H4[(size_t)gr * 16 + c8];
            uint32 w[4] = {v.x, v.y, v.z, v.w};
            uint32 o[4];
#pragma unroll
            for (int p = 0; p < 4; ++p) {
                float f0 = bf2f(w[p] & 0xFFFFu) * s8[2 * p] + t8[2 * p];
                float f1 = bf2f(w[p] >> 16) * s8[2 * p + 1] + t8[2 * p + 1];
                o[p] = pack_bf2(fmaxf(f0, 0.f), fmaxf(f1, 0.f));
            }
            int swz = c8 ^ (r & 15);
            *(uint4*)&As[r * 128 + swz * 8] = make_uint4(o[0], o[1], o[2], o[3]);
        }
    } else {
        // fp32 A path (layer 1: x, no BN)
        const float4* A4 = (const float4*)Af32;
        int c4 = tid & 31;
#pragma unroll
        for (int i = 0; i < 8; ++i) {
            int idx = i * 128 + tid;
            int r = idx >> 5;                   // 0..31
            int gr = row0 + r;
            float4 v = make_float4(0.f, 0.f, 0.f, 0.f);
            if (gr < N_NODES) v = A4[(size_t)gr * 32 + c4];
            ushort4 o;
            o.x = (unsigned short)f2bf(v.x);
            o.y = (unsigned short)f2bf(v.y);
            o.z = (unsigned short)f2bf(v.z);
            o.w = (unsigned short)f2bf(v.w);
            int swz = (c4 >> 1) ^ (r & 15);
            *(ushort4*)&As[r * 128 + swz * 8 + (c4 & 1) * 4] = o;
        }
    }
    __syncthreads();

    int wave = tid >> 6, lane = tid & 63;
    int quad = lane >> 4, l16 = lane & 15;
    int m0 = wave * 16;
    int m = m0 + l16;

    // a-frags: A[m][k = ks*32 + quad*8 + j]
    bf16x8 af[4];
#pragma unroll
    for (int ks = 0; ks < 4; ++ks) {
        int swz = (ks * 4 + quad) ^ (m & 15);
        af[ks] = *(bf16x8*)&As[m * 128 + swz * 8];
    }

    f32x4 acc[8];
#pragma unroll
    for (int nt = 0; nt < 8; ++nt) acc[nt] = (f32x4){0.f, 0.f, 0.f, 0.f};

#pragma unroll
    for (int nt = 0; nt < 8; ++nt) {
        int n = nt * 16 + l16;
        bf16x8 bfr[4];
#pragma unroll
        for (int ks = 0; ks < 4; ++ks)
            bfr[ks] = *(const bf16x8*)&WT[n * 128 + (ks * 4 + quad) * 8];  // global, L2-hot
#pragma unroll
        for (int ks = 0; ks < 4; ++ks)
            acc[nt] = __builtin_amdgcn_mfma_f32_16x16x32_bf16(af[ks], bfr[ks], acc[nt], 0, 0, 0);
    }

    // fused readout partial: out (=|+=) staged @ WfT (+bias). 4 extra MFMAs/wave.
    // Waves own disjoint row ranges -> no double-add.
    if (mode != 0) {
        f32x4 accO = (f32x4){0.f, 0.f, 0.f, 0.f};
#pragma unroll
        for (int ks = 0; ks < 4; ++ks) {
            bf16x8 bw = *(const bf16x8*)&WfT[l16 * 128 + (ks * 4 + quad) * 8];  // tiny, L2-hot
            accO = __builtin_amdgcn_mfma_f32_16x16x32_bf16(af[ks], bw, accO, 0, 0, 0);
        }
        if (l16 < C_OUT) {
#pragma unroll
            for (int reg = 0; reg < 4; ++reg) {
                int gm = row0 + m0 + quad * 4 + reg;
                if (gm < N_NODES) {
                    size_t o = (size_t)gm * C_OUT + l16;
                    float v = accO[reg];
                    if (mode == 1) outp[o] = v + bfv[l16];
                    else outp[o] += v;
                }
            }
        }
    }

    // optional dinv pre-scale factors for this thread's 4 output rows (R16)
    float dv[4] = {1.f, 1.f, 1.f, 1.f};
    if (dinvp) {
#pragma unroll
        for (int reg = 0; reg < 4; ++reg) {
            int gm = row0 + m0 + quad * 4 + reg;
            dv[reg] = (gm < N_NODES) ? dinvp[gm] : 0.f;
        }
    }

    // C-tile: acc -> LDS (bf16, stride CSTR) -> coalesced uint4 stores (full lines)
    __syncthreads();   // all waves done reading As
#pragma unroll
    for (int reg = 0; reg < 4; ++reg) {
        int lm = m0 + quad * 4 + reg;    // local row 0..31
#pragma unroll
        for (int nt = 0; nt < 8; ++nt)
            SM[lm * CSTR + nt * 16 + l16] = (unsigned short)f2bf(acc[nt][reg] * dv[reg]);
    }
    __syncthreads();
    uint4* H4o = (uint4*)hl;
#pragma unroll
    for (int i = 0; i < 4; ++i) {
        int idx = i * 128 + tid;
        int r = idx >> 4, c8 = idx & 15;
        int gr = row0 + r;
        if (gr < N_NODES)
            H4o[(size_t)gr * 16 + c8] = *(uint4*)&SM[r * CSTR + c8 * 8];
    }
}

// ---------------- Aggregation, layer 1 (UNSCALED hl): R6-exact interleaved inner loop.
// wave/node grid-stride, unroll-8, per-edge dinv, bf16 out, fused BN stats.

__global__ __launch_bounds__(256) void k_agg0(const unsigned short* __restrict__ hl,
                                              const int* __restrict__ adj,
                                              const int* __restrict__ cnt,
                                              const float* __restrict__ dinv,
                                              unsigned short* __restrict__ agg,
                                              float* __restrict__ sums) {
    __shared__ float red[4][256];
    int tid = threadIdx.x;
    int lane = tid & 63;
    int gw = (blockIdx.x << 2) | (tid >> 6);      // global wave id
    float sx = 0.f, qx = 0.f, sy = 0.f, qy = 0.f;

    for (int node = gw; node < N_NODES; node += AGG_BLOCKS * 4) {
        const int* row = adj + ((size_t)node << 6);   // wave-uniform scalar reads
        int n = cnt[node];
        float di = dinv[node];
        uint32 ps = *(const uint32*)&hl[(size_t)node * 128 + lane * 2];
        float ax = bf2f(ps & 0xFFFFu) * di;           // self-loop seed
        float ay = bf2f(ps >> 16) * di;
        int e = 0;
        for (; e + 7 < n; e += 8) {
            int j[8];
#pragma unroll
            for (int u = 0; u < 8; ++u) j[u] = row[e + u];
            float w[8];
            uint32 p[8];
#pragma unroll
            for (int u = 0; u < 8; ++u) {
                w[u] = dinv[j[u]];
                p[u] = *(const uint32*)&hl[(size_t)j[u] * 128 + lane * 2];
            }
#pragma unroll
            for (int u = 0; u < 8; ++u) {
                ax += bf2f(p[u] & 0xFFFFu) * w[u];
                ay += bf2f(p[u] >> 16) * w[u];
            }
        }
        for (; e < n; ++e) {
            int j = row[e];
            float w = dinv[j];
            uint32 p = *(const uint32*)&hl[(size_t)j * 128 + lane * 2];
            ax += bf2f(p & 0xFFFFu) * w;
            ay += bf2f(p >> 16) * w;
        }
        float ox = ax * di, oy = ay * di;
        *(uint32*)&agg[(size_t)node * 128 + lane * 2] = pack_bf2(ox, oy);
        sx += ox; qx += ox * ox; sy += oy; qy += oy * oy;
    }

    red[0][tid] = sx; red[1][tid] = qx; red[2][tid] = sy; red[3][tid] = qy;
    __syncthreads();
    int s = tid >> 6, l = tid & 63;
    float v = red[s][l] + red[s][64 + l] + red[s][128 + l] + red[s][192 + l];
    atomicAdd(&sums[((blockIdx.x & (NCOPY - 1)) << 8) + (s & 1) * 128 + 2 * l + (s >> 1)], v);
}

// ---------------- Aggregation, layers 2/3 (hl pre-scaled by dinv in gemm C-store):
// no per-edge dinv gather at all. Same stats epilogue.

__global__ __launch_bounds__(256) void k_agg1(const unsigned short* __restrict__ hl,
                                              const int* __restrict__ adj,
                                              const int* __restrict__ cnt,
                                              const float* __restrict__ dinv,
                                              unsigned short* __restrict__ agg,
                                              float* __restrict__ sums) {
    __shared__ float red[4][256];
    int tid = threadIdx.x;
    int lane = tid & 63;
    int gw = (blockIdx.x << 2) | (tid >> 6);      // global wave id
    float sx = 0.f, qx = 0.f, sy = 0.f, qy = 0.f;

    for (int node = gw; node < N_NODES; node += AGG_BLOCKS * 4) {
        const int* row = adj + ((size_t)node << 6);   // wave-uniform scalar reads
        int n = cnt[node];
        float di = dinv[node];
        uint32 ps = *(const uint32*)&hl[(size_t)node * 128 + lane * 2];
        float ax = bf2f(ps & 0xFFFFu);                // self term already dinv-scaled
        float ay = bf2f(ps >> 16);
        int e = 0;
        for (; e + 7 < n; e += 8) {
            int j[8];
#pragma unroll
            for (int u = 0; u < 8; ++u) j[u] = row[e + u];
            uint32 p[8];
#pragma unroll
            for (int u = 0; u < 8; ++u)
                p[u] = *(const uint32*)&hl[(size_t)j[u] * 128 + lane * 2];
#pragma unroll
            for (int u = 0; u < 8; ++u) {
                ax += bf2f(p[u] & 0xFFFFu);
                ay += bf2f(p[u] >> 16);
            }
        }
        for (; e < n; ++e) {
            int j = row[e];
            uint32 p = *(const uint32*)&hl[(size_t)j * 128 + lane * 2];
            ax += bf2f(p & 0xFFFFu);
            ay += bf2f(p >> 16);
        }
        float ox = ax * di, oy = ay * di;
        *(uint32*)&agg[(size_t)node * 128 + lane * 2] = pack_bf2(ox, oy);
        sx += ox; qx += ox * ox; sy += oy; qy += oy * oy;
    }

    red[0][tid] = sx; red[1][tid] = qx; red[2][tid] = sy; red[3][tid] = qy;
    __syncthreads();
    int s = tid >> 6, l = tid & 63;
    float v = red[s][l] + red[s][64 + l] + red[s][128 + l] + red[s][192 + l];
    atomicAdd(&sums[((blockIdx.x & (NCOPY - 1)) << 8) + (s & 1) * 128 + 2 * l + (s >> 1)], v);
}

// ---------------- Layer-3 readout: MFMA, out += bnrelu(h3) @ WfT-slice2 (32-row tiles) ----

__global__ __launch_bounds__(128) void k_out_mfma(const unsigned short* __restrict__ h,
                                                  const unsigned short* __restrict__ WfT,
                                                  float* __restrict__ outp,
                                                  const float* __restrict__ st) {
    __shared__ unsigned short As[OTILE * 128];  // 8 KB
    int tid = threadIdx.x;
    int row0 = blockIdx.x * OTILE;

    int c8 = tid & 15, cc = c8 * 8;
    float s8[8], t8[8];
    {
        float4 a0 = *(const float4*)&st[cc];
        float4 a1 = *(const float4*)&st[cc + 4];
        float4 b0 = *(const float4*)&st[128 + cc];
        float4 b1 = *(const float4*)&st[128 + cc + 4];
        s8[0] = a0.x; s8[1] = a0.y; s8[2] = a0.z; s8[3] = a0.w;
        s8[4] = a1.x; s8[5] = a1.y; s8[6] = a1.z; s8[7] = a1.w;
        t8[0] = b0.x; t8[1] = b0.y; t8[2] = b0.z; t8[3] = b0.w;
        t8[4] = b1.x; t8[5] = b1.y; t8[6] = b1.z; t8[7] = b1.w;
    }
    const uint4* H4 = (const uint4*)h;
#pragma unroll
    for (int i = 0; i < 4; ++i) {
        int idx = i * 128 + tid;
        int r = idx >> 4;
        int gr = row0 + r;
        uint4 v = make_uint4(0, 0, 0, 0);
        if (gr < N_NODES) v = H4[(size_t)gr * 16 + c8];
        uint32 w[4] = {v.x, v.y, v.z, v.w};
        uint32 o[4];
#pragma unroll
        for (int p = 0; p < 4; ++p) {
            float f0 = bf2f(w[p] & 0xFFFFu) * s8[2 * p] + t8[2 * p];
            float f1 = bf2f(w[p] >> 16) * s8[2 * p + 1] + t8[2 * p + 1];
            o[p] = pack_bf2(fmaxf(f0, 0.f), fmaxf(f1, 0.f));
        }
        int swz = c8 ^ (r & 15);
        *(uint4*)&As[r * 128 + swz * 8] = make_uint4(o[0], o[1], o[2], o[3]);
    }
    __syncthreads();

    int wave = tid >> 6, lane = tid & 63;
    int quad = lane >> 4, l16 = lane & 15;
    int m0 = wave * 16;
    int m = m0 + l16;

    f32x4 accO = (f32x4){0.f, 0.f, 0.f, 0.f};
#pragma unroll
    for (int ks = 0; ks < 4; ++ks) {
        bf16x8 bw = *(const bf16x8*)&WfT[l16 * 128 + (ks * 4 + quad) * 8];
        int swz = (ks * 4 + quad) ^ (m & 15);
        bf16x8 av = *(bf16x8*)&As[m * 128 + swz * 8];
        accO = __builtin_amdgcn_mfma_f32_16x16x32_bf16(av, bw, accO, 0, 0, 0);
    }
    if (l16 < C_OUT) {
#pragma unroll
        for (int reg = 0; reg < 4; ++reg) {
            int gm = row0 + m0 + quad * 4 + reg;
            if (gm < N_NODES)
                outp[(size_t)gm * C_OUT + l16] += accO[reg];
        }
    }
}

// ---------------- launch ----------------

extern "C" void kernel_launch(void* const* d_in, const int* in_sizes, int n_in,
                              void* d_out, int out_size, void* d_ws, size_t ws_size,
                              hipStream_t stream) {
    const float* x  = (const float*)d_in[0];
    const int*   ei = (const int*)d_in[1];
    const float* W1 = (const float*)d_in[2];
    const float* W2 = (const float*)d_in[4];
    const float* W3 = (const float*)d_in[6];
    // b1/b2/b3 absorbed exactly by BN mean-subtraction
    const float* g1  = (const float*)d_in[8];
    const float* be1 = (const float*)d_in[9];
    const float* g2  = (const float*)d_in[10];
    const float* be2 = (const float*)d_in[11];
    const float* g3  = (const float*)d_in[12];
    const float* be3 = (const float*)d_in[13];
    const float* Wf  = (const float*)d_in[14];
    const float* bf  = (const float*)d_in[15];
    float* out = (float*)d_out;

    char* ws = (char*)d_ws;
    size_t off = 0;
    auto alloc = [&](size_t bytes) -> void* {
        void* p = ws + off;
        off = (off + bytes + 255) & ~(size_t)255;
        return p;
    };
    int*   cntp  = (int*)alloc((size_t)N_NODES * 16 * 4);    // 64B-padded counters, 3.2MB
    int*   adj   = (int*)alloc((size_t)N_NODES * CAP * 4);   // 12.8 MB padded rows
    int*   cnt   = (int*)alloc((size_t)N_NODES * 4);
    float* dinv  = (float*)alloc((size_t)N_NODES * 4);
    float* sums  = (float*)alloc((size_t)3 * NCOPY * 256 * 4);  // shadow-copied stats
    float* st    = (float*)alloc((size_t)3 * 256 * 4);          // precomputed BN scale/shift
    unsigned short* WT   = (unsigned short*)alloc((size_t)3 * 128 * 128 * 2);
    unsigned short* WfT  = (unsigned short*)alloc((size_t)3 * 16 * 128 * 2);
    unsigned short* hl   = (unsigned short*)alloc((size_t)N_NODES * 128 * 2);  // bf16
    unsigned short* bufA = (unsigned short*)alloc((size_t)N_NODES * 128 * 2);  // bf16 agg
    unsigned short* bufB = (unsigned short*)alloc((size_t)N_NODES * 128 * 2);  // bf16 agg

    const int TPB = 256;
    const int SL = NCOPY * 256;   // per-layer sums stride
    k_setup<<<412, 256, 0, stream>>>(W1, W2, W3, Wf, WT, WfT, cntp, sums);

    // ---- layer 1 GEMM fused with direct adjacency build (gemm tiles FIRST) ----
    k_gemm<<<GEMM_GRID + LINKB, 128, 0, stream>>>(
        x, nullptr, WT, hl, nullptr, nullptr,
        nullptr, nullptr, 0, nullptr, ei, cntp, adj);
    k_dinv<<<(N_NODES + TPB - 1) / TPB, TPB, 0, stream>>>(cntp, cnt, dinv);
    k_agg0<<<AGG_BLOCKS, 256, 0, stream>>>(hl, adj, cnt, dinv, bufA, sums + 0);
    k_bnfin<<<1, 128, 0, stream>>>(sums + 0, g1, be1, st + 0);

    // ---- layer 2 (gemm also emits out = h1 @ Wf0 + bf; hl pre-scaled by dinv) ----
    k_gemm<<<GEMM_GRID, 128, 0, stream>>>(nullptr, bufA, WT + 16384, hl, st + 0,
                                          WfT, bf, out, 1, dinv, nullptr, nullptr, nullptr);
    k_agg1<<<AGG_BLOCKS, 256, 0, stream>>>(hl, adj, cnt, dinv, bufB, sums + SL);
    k_bnfin<<<1, 128, 0, stream>>>(sums + SL, g2, be2, st + 256);

    // ---- layer 3 (gemm also emits out += h2 @ Wf1; hl pre-scaled by dinv) ----
    k_gemm<<<GEMM_GRID, 128, 0, stream>>>(nullptr, bufB, WT + 32768, hl, st + 256,
                                          WfT + 2048, nullptr, out, 2, dinv,
                                          nullptr, nullptr, nullptr);
    k_agg1<<<AGG_BLOCKS, 256, 0, stream>>>(hl, adj, cnt, dinv, bufA, sums + 2 * SL);
    k_bnfin<<<1, 128, 0, stream>>>(sums + 2 * SL, g3, be3, st + 512);

    // ---- layer 3 readout (MFMA) ----
    k_out_mfma<<<OUT_GRID, 128, 0, stream>>>(bufA, WfT + 4096, out, st + 512);
}

// Round 12
// 321.808 us; speedup vs baseline: 1.3182x; 1.0152x over previous
//
#include <hip/hip_runtime.h>

#define N_NODES 50000
#define N_EDGES 800000
#define D 128
#define C_OUT 10
#define BN_EPS 1e-5f
#define CAP 64            // padded adjacency row capacity; P(deg>=63)~1e-17 (Poisson 16)
#define MTILE 32          // R19: 32 is the tile knee (16 regressed: fixed overhead; 128: occ)
#define GEMM_GRID 1563    // ceil(50000/32)
#define OTILE 32          // out_mfma 32-row tiles
#define OUT_GRID 1563     // ceil(50000/32)
#define LINKB 782         // link blocks appended AFTER gemm tiles; 782*128*8 >= E
#define AGG_BLOCKS 2048   // 8 blocks/CU resident; whole grid co-resident
#define NCOPY 32          // BN-stats shadow copies (R13)
#define CSTR 136          // LDS C-dump row stride (ushorts): quad writes 2-way max

// R20: (a) adj slots are ushort (node ids < 65536) — halves the scatter line ping-pong
// (~45MB of the fused dispatch's 61MB WRITE was adj cross-XCD line bounce) and halves
// agg's adj reads. (b) gemm B-fragments preloaded in two 16-load halves into registers
// (VGPR was 48 = acc+af exactly -> zero load hoisting, serialized load-wait-mfma;
// residency is grid-limited ~12 waves/CU so VGPRs are free) + __launch_bounds__(128,1).
// R18: k_agg0/k_agg1 compile-time split (runtime branch cost ~20us codegen). KEPT.
// R16: gemm2/3 C-store pre-scales rows by dinv so k_agg1 skips per-edge dinv. KEPT.
// R17: last-block-ticket bnfin REVERTED (single-address value-returning atomics).
// R21: resubmit of R20 unchanged (round-11 bench was an infra failure, no data).

typedef unsigned int uint32;
typedef __attribute__((ext_vector_type(8))) short bf16x8;
typedef __attribute__((ext_vector_type(4))) float f32x4;

__device__ __forceinline__ float bf2f(unsigned int u16) {
    unsigned int x = u16 << 16;
    float f;
    __builtin_memcpy(&f, &x, 4);
    return f;
}
__device__ __forceinline__ unsigned int f2bf(float f) {
    unsigned int x;
    __builtin_memcpy(&x, &f, 4);
    unsigned int r = x + 0x7FFFu + ((x >> 16) & 1u);  // RNE
    return r >> 16;
}
__device__ __forceinline__ uint32 pack_bf2(float a, float b) {
    return f2bf(a) | (f2bf(b) << 16);
}

// ---------------- setup: W^T bf16, Wf^T bf16, cntp=0 (64B-padded), sums=0 ----------

__global__ void k_setup(const float* __restrict__ W1, const float* __restrict__ W2,
                        const float* __restrict__ W3, const float* __restrict__ Wf,
                        unsigned short* __restrict__ WT, unsigned short* __restrict__ WfT,
                        int* __restrict__ cntp, float* __restrict__ sums) {
    int b = blockIdx.x, tid = threadIdx.x;
    if (b < 192) {                       // WT: 3 x 128 x 128
        int idx = b * 256 + tid;
        int mat = idx >> 14, rem = idx & 16383;
        int n = rem >> 7, k = rem & 127;
        const float* W = (mat == 0) ? W1 : ((mat == 1) ? W2 : W3);
        WT[idx] = (unsigned short)f2bf(W[k * 128 + n]);
    } else if (b < 216) {                // WfT: 3 slices x 16(n,pad) x 128(k)
        int idx = (b - 192) * 256 + tid;
        if (idx < 6144) {
            int li = idx >> 11, rem = idx & 2047;
            int n = rem >> 7, k = rem & 127;
            WfT[idx] = (n < C_OUT) ? (unsigned short)f2bf(Wf[(li * 128 + k) * C_OUT + n]) : 0;
        }
    } else {                             // per-node atomic counter init + sums zero
        int i = (b - 216) * 256 + tid;
        if (i < N_NODES) cntp[i << 4] = 0;   // one counter per 64B line (atomic de-contention)
        if (i < 3 * NCOPY * 256) sums[i] = 0.0f;
    }
}

// ---------------- compact deg: cnt (stored edges) + dinv = rsqrt(deg+1) ----------

__global__ void k_dinv(const int* __restrict__ cntp, int* __restrict__ cnt,
                       float* __restrict__ dinv) {
    int i = blockIdx.x * blockDim.x + threadIdx.x;
    if (i >= N_NODES) return;
    int c = cntp[i << 4];                        // in-edges (excl self)
    cnt[i] = (c < CAP) ? c : CAP;                // stored slots
    dinv[i] = rsqrtf((float)(c + 1));            // exact deg incl self (matches ref)
}

// ---------------- BN finalize: reduce NCOPY shadow copies -> scale/shift st[2][128] ----

__global__ void k_bnfin(const float* __restrict__ sums, const float* __restrict__ g,
                        const float* __restrict__ be, float* __restrict__ st) {
    int t = threadIdx.x;      // 128 threads
    float sm = 0.f, sq = 0.f;
    for (int c = 0; c < NCOPY; ++c) {
        sm += sums[c * 256 + t];
        sq += sums[c * 256 + 128 + t];
    }
    float mean = sm * (1.0f / N_NODES);
    float var = fmaxf(sq * (1.0f / N_NODES) - mean * mean, 0.f);
    float s = g[t] * rsqrtf(var + BN_EPS);
    st[t] = s;
    st[128 + t] = be[t] - mean * s;
}

// ---------------- MFMA GEMM (+ optional fused adjacency build, BN prologue, readout)
// 32-row tiles, 128 threads = 2 waves; wave w owns rows [w*16, w*16+16) x all 128 cols.
// hl[M,128](bf16) = bnrelu(A) @ W; if dinvp: rows pre-scaled by dinv (R16).
// A: Af32 (layer1) XOR Abf (bf16, BN'd via st). W read DIRECTLY from global WT (R14),
// preloaded in two 16-load register halves for MLP (R20).
// C-tile: acc -> LDS (stride CSTR) -> coalesced uint4 store (R10).
// If linkEi: blocks [GEMM_GRID, GEMM_GRID+LINKB) do the direct slot build (ushort slots).
// mode: 0=none, 1=out = staged@WfT + bias, 2=out += staged@WfT.

__global__ __launch_bounds__(128, 1) void k_gemm(const float* __restrict__ Af32,
                                                 const unsigned short* __restrict__ Abf,
                                                 const unsigned short* __restrict__ WT,
                                                 unsigned short* __restrict__ hl,
                                                 const float* __restrict__ st,
                                                 const unsigned short* __restrict__ WfT,
                                                 const float* __restrict__ bfv,
                                                 float* __restrict__ outp, int mode,
                                                 const float* __restrict__ dinvp,
                                                 const int* __restrict__ linkEi,
                                                 int* __restrict__ cntp,
                                                 unsigned short* __restrict__ adj) {
    __shared__ unsigned short SM[MTILE * CSTR];   // 8.7 KB
    unsigned short* As = SM;
    int tid = threadIdx.x;
    int bid = blockIdx.x;

    if (linkEi && bid >= GEMM_GRID) {
        // direct adjacency build: 8 edges/thread, independent atomics (ILP)
        int lb = bid - GEMM_GRID;
        int d8[8], s8[8];
#pragma unroll
        for (int u = 0; u < 8; ++u) {
            int e = (lb * 8 + u) * 128 + tid;
            d8[u] = (e < N_EDGES) ? linkEi[N_EDGES + e] : -1;   // destination
            s8[u] = (e < N_EDGES) ? linkEi[e] : 0;              // source
        }
#pragma unroll
        for (int u = 0; u < 8; ++u) {
            if (d8[u] >= 0) {
                int slot = atomicAdd(&cntp[d8[u] << 4], 1);
                if (slot < CAP) adj[(d8[u] << 6) + slot] = (unsigned short)s8[u];
            }
        }
        return;
    }
    int row0 = bid * MTILE;

    if (Abf) {
        // bf16 A path: thread stages 2 rows of its fixed column octet (c8 = tid&15)
        int c8 = tid & 15, cc = c8 * 8;
        float s8[8], t8[8];
        {
            float4 a0 = *(const float4*)&st[cc];
            float4 a1 = *(const float4*)&st[cc + 4];
            float4 b0 = *(const float4*)&st[128 + cc];
            float4 b1 = *(const float4*)&st[128 + cc + 4];
            s8[0] = a0.x; s8[1] = a0.y; s8[2] = a0.z; s8[3] = a0.w;
            s8[4] = a1.x; s8[5] = a1.y; s8[6] = a1.z; s8[7] = a1.w;
            t8[0] = b0.x; t8[1] = b0.y; t8[2] = b0.z; t8[3] = b0.w;
            t8[4] = b1.x; t8[5] = b1.y; t8[6] = b1.z; t8[7] = b1.w;
        }
        const uint4* H4 = (const uint4*)Abf;
#pragma unroll
        for (int i = 0; i < 4; ++i) {
            int idx = i * 128 + tid;
            int r = idx >> 4;                   // 0..31
            int gr = row0 + r;
            uint4 v = make_uint4(0, 0, 0, 0);
            if (gr < N_NODES) v = H4[(size_t)gr * 16 + c8];
            uint32 w[4] = {v.x, v.y, v.z, v.w};
            uint32 o[4];
#pragma unroll
            for (int p = 0; p < 4; ++p) {
                float f0 = bf2f(w[p] & 0xFFFFu) * s8[2 * p] + t8[2 * p];
                float f1 = bf2f(w[p] >> 16) * s8[2 * p + 1] + t8[2 * p + 1];
                o[p] = pack_bf2(fmaxf(f0, 0.f), fmaxf(f1, 0.f));
            }
            int swz = c8 ^ (r & 15);
            *(uint4*)&As[r * 128 + swz * 8] = make_uint4(o[0], o[1], o[2], o[3]);
        }
    } else {
        // fp32 A path (layer 1: x, no BN)
        const float4* A4 = (const float4*)Af32;
        int c4 = tid & 31;
#pragma unroll
        for (int i = 0; i < 8; ++i) {
            int idx = i * 128 + tid;
            int r = idx >> 5;                   // 0..31
            int gr = row0 + r;
            float4 v = make_float4(0.f, 0.f, 0.f, 0.f);
            if (gr < N_NODES) v = A4[(size_t)gr * 32 + c4];
            ushort4 o;
            o.x = (unsigned short)f2bf(v.x);
            o.y = (unsigned short)f2bf(v.y);
            o.z = (unsigned short)f2bf(v.z);
            o.w = (unsigned short)f2bf(v.w);
            int swz = (c4 >> 1) ^ (r & 15);
            *(ushort4*)&As[r * 128 + swz * 8 + (c4 & 1) * 4] = o;
        }
    }
    __syncthreads();

    int wave = tid >> 6, lane = tid & 63;
    int quad = lane >> 4, l16 = lane & 15;
    int m0 = wave * 16;
    int m = m0 + l16;

    // a-frags: A[m][k = ks*32 + quad*8 + j]
    bf16x8 af[4];
#pragma unroll
    for (int ks = 0; ks < 4; ++ks) {
        int swz = (ks * 4 + quad) ^ (m & 15);
        af[ks] = *(bf16x8*)&As[m * 128 + swz * 8];
    }

    f32x4 acc[8];
#pragma unroll
    for (int nt = 0; nt < 8; ++nt) acc[nt] = (f32x4){0.f, 0.f, 0.f, 0.f};

    // R20: two-half register preload of B-fragments — 16 loads in flight per half
    // (16KB/wave) instead of 4, hiding L2 latency under the MFMA stream.
#pragma unroll
    for (int half = 0; half < 2; ++half) {
        bf16x8 bfr[4][4];
#pragma unroll
        for (int nt = 0; nt < 4; ++nt) {
            int n = (half * 4 + nt) * 16 + l16;
#pragma unroll
            for (int ks = 0; ks < 4; ++ks)
                bfr[nt][ks] = *(const bf16x8*)&WT[n * 128 + (ks * 4 + quad) * 8];
        }
#pragma unroll
        for (int nt = 0; nt < 4; ++nt)
#pragma unroll
            for (int ks = 0; ks < 4; ++ks)
                acc[half * 4 + nt] = __builtin_amdgcn_mfma_f32_16x16x32_bf16(
                    af[ks], bfr[nt][ks], acc[half * 4 + nt], 0, 0, 0);
    }

    // fused readout partial: out (=|+=) staged @ WfT (+bias). 4 extra MFMAs/wave.
    // Waves own disjoint row ranges -> no double-add.
    if (mode != 0) {
        f32x4 accO = (f32x4){0.f, 0.f, 0.f, 0.f};
#pragma unroll
        for (int ks = 0; ks < 4; ++ks) {
            bf16x8 bw = *(const bf16x8*)&WfT[l16 * 128 + (ks * 4 + quad) * 8];  // tiny, L2-hot
            accO = __builtin_amdgcn_mfma_f32_16x16x32_bf16(af[ks], bw, accO, 0, 0, 0);
        }
        if (l16 < C_OUT) {
#pragma unroll
            for (int reg = 0; reg < 4; ++reg) {
                int gm = row0 + m0 + quad * 4 + reg;
                if (gm < N_NODES) {
                    size_t o = (size_t)gm * C_OUT + l16;
                    float v = accO[reg];
                    if (mode == 1) outp[o] = v + bfv[l16];
                    else outp[o] += v;
                }
            }
        }
    }

    // optional dinv pre-scale factors for this thread's 4 output rows (R16)
    float dv[4] = {1.f, 1.f, 1.f, 1.f};
    if (dinvp) {
#pragma unroll
        for (int reg = 0; reg < 4; ++reg) {
            int gm = row0 + m0 + quad * 4 + reg;
            dv[reg] = (gm < N_NODES) ? dinvp[gm] : 0.f;
        }
    }

    // C-tile: acc -> LDS (bf16, stride CSTR) -> coalesced uint4 stores (full lines)
    __syncthreads();   // all waves done reading As
#pragma unroll
    for (int reg = 0; reg < 4; ++reg) {
        int lm = m0 + quad * 4 + reg;    // local row 0..31
#pragma unroll
        for (int nt = 0; nt < 8; ++nt)
            SM[lm * CSTR + nt * 16 + l16] = (unsigned short)f2bf(acc[nt][reg] * dv[reg]);
    }
    __syncthreads();
    uint4* H4o = (uint4*)hl;
#pragma unroll
    for (int i = 0; i < 4; ++i) {
        int idx = i * 128 + tid;
        int r = idx >> 4, c8 = idx & 15;
        int gr = row0 + r;
        if (gr < N_NODES)
            H4o[(size_t)gr * 16 + c8] = *(uint4*)&SM[r * CSTR + c8 * 8];
    }
}

// ---------------- Aggregation, layer 1 (UNSCALED hl): R6-exact interleaved inner loop.
// wave/node grid-stride, unroll-8, per-edge dinv, bf16 out, fused BN stats.
// adj rows are ushort (R20).

__global__ __launch_bounds__(256) void k_agg0(const unsigned short* __restrict__ hl,
                                              const unsigned short* __restrict__ adj,
                                              const int* __restrict__ cnt,
                                              const float* __restrict__ dinv,
                                              unsigned short* __restrict__ agg,
                                              float* __restrict__ sums) {
    __shared__ float red[4][256];
    int tid = threadIdx.x;
    int lane = tid & 63;
    int gw = (blockIdx.x << 2) | (tid >> 6);      // global wave id
    float sx = 0.f, qx = 0.f, sy = 0.f, qy = 0.f;

    for (int node = gw; node < N_NODES; node += AGG_BLOCKS * 4) {
        const unsigned short* row = adj + ((size_t)node << 6);  // wave-uniform reads
        int n = cnt[node];
        float di = dinv[node];
        uint32 ps = *(const uint32*)&hl[(size_t)node * 128 + lane * 2];
        float ax = bf2f(ps & 0xFFFFu) * di;           // self-loop seed
        float ay = bf2f(ps >> 16) * di;
        int e = 0;
        for (; e + 7 < n; e += 8) {
            int j[8];
#pragma unroll
            for (int u = 0; u < 8; ++u) j[u] = row[e + u];
            float w[8];
            uint32 p[8];
#pragma unroll
            for (int u = 0; u < 8; ++u) {
                w[u] = dinv[j[u]];
                p[u] = *(const uint32*)&hl[(size_t)j[u] * 128 + lane * 2];
            }
#pragma unroll
            for (int u = 0; u < 8; ++u) {
                ax += bf2f(p[u] & 0xFFFFu) * w[u];
                ay += bf2f(p[u] >> 16) * w[u];
            }
        }
        for (; e < n; ++e) {
            int j = row[e];
            float w = dinv[j];
            uint32 p = *(const uint32*)&hl[(size_t)j * 128 + lane * 2];
            ax += bf2f(p & 0xFFFFu) * w;
            ay += bf2f(p >> 16) * w;
        }
        float ox = ax * di, oy = ay * di;
        *(uint32*)&agg[(size_t)node * 128 + lane * 2] = pack_bf2(ox, oy);
        sx += ox; qx += ox * ox; sy += oy; qy += oy * oy;
    }

    red[0][tid] = sx; red[1][tid] = qx; red[2][tid] = sy; red[3][tid] = qy;
    __syncthreads();
    int s = tid >> 6, l = tid & 63;
    float v = red[s][l] + red[s][64 + l] + red[s][128 + l] + red[s][192 + l];
    atomicAdd(&sums[((blockIdx.x & (NCOPY - 1)) << 8) + (s & 1) * 128 + 2 * l + (s >> 1)], v);
}

// ---------------- Aggregation, layers 2/3 (hl pre-scaled by dinv in gemm C-store):
// no per-edge dinv gather at all. Same stats epilogue. adj rows are ushort (R20).

__global__ __launch_bounds__(256) void k_agg1(const unsigned short* __restrict__ hl,
                                              const unsigned short* __restrict__ adj,
                                              const int* __restrict__ cnt,
                                              const float* __restrict__ dinv,
                                              unsigned short* __restrict__ agg,
                                              float* __restrict__ sums) {
    __shared__ float red[4][256];
    int tid = threadIdx.x;
    int lane = tid & 63;
    int gw = (blockIdx.x << 2) | (tid >> 6);      // global wave id
    float sx = 0.f, qx = 0.f, sy = 0.f, qy = 0.f;

    for (int node = gw; node < N_NODES; node += AGG_BLOCKS * 4) {
        const unsigned short* row = adj + ((size_t)node << 6);  // wave-uniform reads
        int n = cnt[node];
        float di = dinv[node];
        uint32 ps = *(const uint32*)&hl[(size_t)node * 128 + lane * 2];
        float ax = bf2f(ps & 0xFFFFu);                // self term already dinv-scaled
        float ay = bf2f(ps >> 16);
        int e = 0;
        for (; e + 7 < n; e += 8) {
            int j[8];
#pragma unroll
            for (int u = 0; u < 8; ++u) j[u] = row[e + u];
            uint32 p[8];
#pragma unroll
            for (int u = 0; u < 8; ++u)
                p[u] = *(const uint32*)&hl[(size_t)j[u] * 128 + lane * 2];
#pragma unroll
            for (int u = 0; u < 8; ++u) {
                ax += bf2f(p[u] & 0xFFFFu);
                ay += bf2f(p[u] >> 16);
            }
        }
        for (; e < n; ++e) {
            int j = row[e];
            uint32 p = *(const uint32*)&hl[(size_t)j * 128 + lane * 2];
            ax += bf2f(p & 0xFFFFu);
            ay += bf2f(p >> 16);
        }
        float ox = ax * di, oy = ay * di;
        *(uint32*)&agg[(size_t)node * 128 + lane * 2] = pack_bf2(ox, oy);
        sx += ox; qx += ox * ox; sy += oy; qy += oy * oy;
    }

    red[0][tid] = sx; red[1][tid] = qx; red[2][tid] = sy; red[3][tid] = qy;
    __syncthreads();
    int s = tid >> 6, l = tid & 63;
    float v = red[s][l] + red[s][64 + l] + red[s][128 + l] + red[s][192 + l];
    atomicAdd(&sums[((blockIdx.x & (NCOPY - 1)) << 8) + (s & 1) * 128 + 2 * l + (s >> 1)], v);
}

// ---------------- Layer-3 readout: MFMA, out += bnrelu(h3) @ WfT-slice2 (32-row tiles) ----

__global__ __launch_bounds__(128) void k_out_mfma(const unsigned short* __restrict__ h,
                                                  const unsigned short* __restrict__ WfT,
                                                  float* __restrict__ outp,
                                                  const float* __restrict__ st) {
    __shared__ unsigned short As[OTILE * 128];  // 8 KB
    int tid = threadIdx.x;
    int row0 = blockIdx.x * OTILE;

    int c8 = tid & 15, cc = c8 * 8;
    float s8[8], t8[8];
    {
        float4 a0 = *(const float4*)&st[cc];
        float4 a1 = *(const float4*)&st[cc + 4];
        float4 b0 = *(const float4*)&st[128 + cc];
        float4 b1 = *(const float4*)&st[128 + cc + 4];
        s8[0] = a0.x; s8[1] = a0.y; s8[2] = a0.z; s8[3] = a0.w;
        s8[4] = a1.x; s8[5] = a1.y; s8[6] = a1.z; s8[7] = a1.w;
        t8[0] = b0.x; t8[1] = b0.y; t8[2] = b0.z; t8[3] = b0.w;
        t8[4] = b1.x; t8[5] = b1.y; t8[6] = b1.z; t8[7] = b1.w;
    }
    const uint4* H4 = (const uint4*)h;
#pragma unroll
    for (int i = 0; i < 4; ++i) {
        int idx = i * 128 + tid;
        int r = idx >> 4;
        int gr = row0 + r;
        uint4 v = make_uint4(0, 0, 0, 0);
        if (gr < N_NODES) v = H4[(size_t)gr * 16 + c8];
        uint32 w[4] = {v.x, v.y, v.z, v.w};
        uint32 o[4];
#pragma unroll
        for (int p = 0; p < 4; ++p) {
            float f0 = bf2f(w[p] & 0xFFFFu) * s8[2 * p] + t8[2 * p];
            float f1 = bf2f(w[p] >> 16) * s8[2 * p + 1] + t8[2 * p + 1];
            o[p] = pack_bf2(fmaxf(f0, 0.f), fmaxf(f1, 0.f));
        }
        int swz = c8 ^ (r & 15);
        *(uint4*)&As[r * 128 + swz * 8] = make_uint4(o[0], o[1], o[2], o[3]);
    }
    __syncthreads();

    int wave = tid >> 6, lane = tid & 63;
    int quad = lane >> 4, l16 = lane & 15;
    int m0 = wave * 16;
    int m = m0 + l16;

    f32x4 accO = (f32x4){0.f, 0.f, 0.f, 0.f};
#pragma unroll
    for (int ks = 0; ks < 4; ++ks) {
        bf16x8 bw = *(const bf16x8*)&WfT[l16 * 128 + (ks * 4 + quad) * 8];
        int swz = (ks * 4 + quad) ^ (m & 15);
        bf16x8 av = *(bf16x8*)&As[m * 128 + swz * 8];
        accO = __builtin_amdgcn_mfma_f32_16x16x32_bf16(av, bw, accO, 0, 0, 0);
    }
    if (l16 < C_OUT) {
#pragma unroll
        for (int reg = 0; reg < 4; ++reg) {
            int gm = row0 + m0 + quad * 4 + reg;
            if (gm < N_NODES)
                outp[(size_t)gm * C_OUT + l16] += accO[reg];
        }
    }
}

// ---------------- launch ----------------

extern "C" void kernel_launch(void* const* d_in, const int* in_sizes, int n_in,
                              void* d_out, int out_size, void* d_ws, size_t ws_size,
                              hipStream_t stream) {
    const float* x  = (const float*)d_in[0];
    const int*   ei = (const int*)d_in[1];
    const float* W1 = (const float*)d_in[2];
    const float* W2 = (const float*)d_in[4];
    const float* W3 = (const float*)d_in[6];
    // b1/b2/b3 absorbed exactly by BN mean-subtraction
    const float* g1  = (const float*)d_in[8];
    const float* be1 = (const float*)d_in[9];
    const float* g2  = (const float*)d_in[10];
    const float* be2 = (const float*)d_in[11];
    const float* g3  = (const float*)d_in[12];
    const float* be3 = (const float*)d_in[13];
    const float* Wf  = (const float*)d_in[14];
    const float* bf  = (const float*)d_in[15];
    float* out = (float*)d_out;

    char* ws = (char*)d_ws;
    size_t off = 0;
    auto alloc = [&](size_t bytes) -> void* {
        void* p = ws + off;
        off = (off + bytes + 255) & ~(size_t)255;
        return p;
    };
    int*   cntp  = (int*)alloc((size_t)N_NODES * 16 * 4);    // 64B-padded counters, 3.2MB
    unsigned short* adj = (unsigned short*)alloc((size_t)N_NODES * CAP * 2);  // 6.4MB ushort rows
    int*   cnt   = (int*)alloc((size_t)N_NODES * 4);
    float* dinv  = (float*)alloc((size_t)N_NODES * 4);
    float* sums  = (float*)alloc((size_t)3 * NCOPY * 256 * 4);  // shadow-copied stats
    float* st    = (float*)alloc((size_t)3 * 256 * 4);          // precomputed BN scale/shift
    unsigned short* WT   = (unsigned short*)alloc((size_t)3 * 128 * 128 * 2);
    unsigned short* WfT  = (unsigned short*)alloc((size_t)3 * 16 * 128 * 2);
    unsigned short* hl   = (unsigned short*)alloc((size_t)N_NODES * 128 * 2);  // bf16
    unsigned short* bufA = (unsigned short*)alloc((size_t)N_NODES * 128 * 2);  // bf16 agg
    unsigned short* bufB = (unsigned short*)alloc((size_t)N_NODES * 128 * 2);  // bf16 agg

    const int TPB = 256;
    const int SL = NCOPY * 256;   // per-layer sums stride
    k_setup<<<412, 256, 0, stream>>>(W1, W2, W3, Wf, WT, WfT, cntp, sums);

    // ---- layer 1 GEMM fused with direct adjacency build (gemm tiles FIRST) ----
    k_gemm<<<GEMM_GRID + LINKB, 128, 0, stream>>>(
        x, nullptr, WT, hl, nullptr, nullptr,
        nullptr, nullptr, 0, nullptr, ei, cntp, adj);
    k_dinv<<<(N_NODES + TPB - 1) / TPB, TPB, 0, stream>>>(cntp, cnt, dinv);
    k_agg0<<<AGG_BLOCKS, 256, 0, stream>>>(hl, adj, cnt, dinv, bufA, sums + 0);
    k_bnfin<<<1, 128, 0, stream>>>(sums + 0, g1, be1, st + 0);

    // ---- layer 2 (gemm also emits out = h1 @ Wf0 + bf; hl pre-scaled by dinv) ----
    k_gemm<<<GEMM_GRID, 128, 0, stream>>>(nullptr, bufA, WT + 16384, hl, st + 0,
                                          WfT, bf, out, 1, dinv, nullptr, nullptr, nullptr);
    k_agg1<<<AGG_BLOCKS, 256, 0, stream>>>(hl, adj, cnt, dinv, bufB, sums + SL);
    k_bnfin<<<1, 128, 0, stream>>>(sums + SL, g2, be2, st + 256);

    // ---- layer 3 (gemm also emits out += h2 @ Wf1; hl pre-scaled by dinv) ----
    k_gemm<<<GEMM_GRID, 128, 0, stream>>>(nullptr, bufB, WT + 32768, hl, st + 256,
                                          WfT + 2048, nullptr, out, 2, dinv,
                                          nullptr, nullptr, nullptr);
    k_agg1<<<AGG_BLOCKS, 256, 0, stream>>>(hl, adj, cnt, dinv, bufA, sums + 2 * SL);
    k_bnfin<<<1, 128, 0, stream>>>(sums + 2 * SL, g3, be3, st + 512);

    // ---- layer 3 readout (MFMA) ----
    k_out_mfma<<<OUT_GRID, 128, 0, stream>>>(bufA, WfT + 4096, out, st + 512);
}